// Round 3
// baseline (2809.875 us; speedup 1.0000x reference)
//
#include <hip/hip_runtime.h>
#include <hip/hip_bf16.h>

#define NATOMS 2048
#define K 48
#define P (NATOMS * K)
#define NR 5
#define NM 12
#define ND 17
#define HID 64

#define PI_F 3.14159265358979f
#define CUT 3.0f
#define RMIN_F 3.5f
#define AFC (-6.28318530717959f)   /* pi/(CUT-RMIN) = pi/(-0.5) */
#define POC (PI_F / CUT)           /* pi/3 */
#define SQ 0.816496580927726f      /* sqrt(2/3) */

// Scratch in device globals (fully rewritten every call before any read).
__device__ float g_desc[ND * P];   // transposed: [feature][pair]
__device__ float g_gdesc[ND * P];  // transposed: [feature][pair]
__device__ float g_eij[P];

__device__ __forceinline__ float fast_tanh(float x) {
    float cx = fminf(fmaxf(x, -15.0f), 15.0f);
    float t = __expf(2.0f * cx);
    return (t - 1.0f) / (t + 1.0f);
}

// ---------------- Kernel 1: per-atom forward (rbf + 3-body descriptors) ---
__global__ __launch_bounds__(256) void k_fwd_atom(const float* __restrict__ rij) {
    __shared__ float su[K][3];
    __shared__ float sfcrik[K];
    __shared__ float sc[K][K + 1];
    const int atom = blockIdx.x, t = threadIdx.x, base = atom * K;

    if (t < K) {
        const float x = rij[3 * (base + t) + 0];
        const float y = rij[3 * (base + t) + 1];
        const float z = rij[3 * (base + t) + 2];
        const float d = sqrtf(x * x + y * y + z * z);
        const float inv = 1.0f / fmaxf(d, 1e-12f);
        su[t][0] = x * inv; su[t][1] = y * inv; su[t][2] = z * inv;
        sfcrik[t] = 0.5f + 0.5f * __cosf(POC * d);
        const float fc = (d > RMIN_F) ? (0.5f + 0.5f * __cosf(AFC * (d - RMIN_F))) : 1.0f;
        const float s = SQ * fc / d;
#pragma unroll
        for (int n = 0; n < NR; n++) {
            const float bn = (float)(n + 1) * POC;
            g_desc[n * P + base + t] = s * __sinf(bn * d);
        }
    }
    __syncthreads();

    for (int idx = t; idx < K * K; idx += 256) {
        const int k = idx / K, l = idx - k * K;
        const float c = su[k][0] * su[l][0] + su[k][1] * su[l][1] + su[k][2] * su[l][2];
        sc[k][l] = (k == l) ? 0.0f : c;
    }
    __syncthreads();

    for (int idx = t; idx < K * NM; idx += 256) {
        const int k = idx / NM, m = idx - k * NM;
        const float mu = -1.0f + (2.0f / 11.0f) * (float)m;
        float s = 0.0f;
#pragma unroll 4
        for (int l = 0; l < K; l++) {
            const float df = sc[k][l] - mu;
            s = fmaf(__expf(-4.0f * df * df), sfcrik[l], s);
        }
        g_desc[(NR + m) * P + base + k] = s;
    }
}

// ---------------- Kernel 2: per-pair MLP forward + backward ---------------
// Weights staged in LDS: wave-uniform ds_read broadcasts (conflict-free),
// replacing the s_load latency chains that made round 2 run at ~77 cyc/FMA.
#define MLP_BLK 128
__global__ __launch_bounds__(MLP_BLK, 1) void k_mlp(const float* __restrict__ rij,
                                                    const float* __restrict__ W1,
                                                    const float* __restrict__ b1,
                                                    const float* __restrict__ W2,
                                                    const float* __restrict__ b2,
                                                    const float* __restrict__ W3,
                                                    const float* __restrict__ b3) {
    __shared__ float sW1[ND * HID];
    __shared__ float sW2[HID * HID];
    __shared__ float sW3[HID];
    __shared__ float sb1[HID];
    __shared__ float sb2[HID];
    const int t = threadIdx.x;
    for (int i = t; i < ND * HID; i += MLP_BLK) sW1[i] = W1[i];
    for (int i = t; i < HID * HID; i += MLP_BLK) sW2[i] = W2[i];
    if (t < HID) { sW3[t] = W3[t]; sb1[t] = b1[t]; sb2[t] = b2[t]; }
    const float b3v = b3[0];
    __syncthreads();

    const float4* __restrict__ sW1_4 = (const float4*)sW1;
    const float4* __restrict__ sW2_4 = (const float4*)sW2;
    const float4* __restrict__ sW3_4 = (const float4*)sW3;

    const int p = blockIdx.x * MLP_BLK + t;

    const float x = rij[3 * p], y = rij[3 * p + 1], z = rij[3 * p + 2];
    const float d = sqrtf(x * x + y * y + z * z);
    const float fc = (d > RMIN_F) ? (0.5f + 0.5f * __cosf(AFC * (d - RMIN_F))) : 1.0f;

    // layer 1
    float h1[HID];
#pragma unroll
    for (int h = 0; h < HID; h++) h1[h] = sb1[h];
#pragma unroll
    for (int j = 0; j < ND; j++) {
        const float dj = g_desc[j * P + p];
#pragma unroll
        for (int h4 = 0; h4 < HID / 4; h4++) {
            const float4 w = sW1_4[j * (HID / 4) + h4];
            h1[4 * h4 + 0] = fmaf(dj, w.x, h1[4 * h4 + 0]);
            h1[4 * h4 + 1] = fmaf(dj, w.y, h1[4 * h4 + 1]);
            h1[4 * h4 + 2] = fmaf(dj, w.z, h1[4 * h4 + 2]);
            h1[4 * h4 + 3] = fmaf(dj, w.w, h1[4 * h4 + 3]);
        }
    }
#pragma unroll
    for (int h = 0; h < HID; h++) h1[h] = fast_tanh(h1[h]);

    // layer 2
    float a2[HID];
#pragma unroll
    for (int h = 0; h < HID; h++) a2[h] = sb2[h];
#pragma unroll
    for (int j = 0; j < HID; j++) {
        const float hj = h1[j];
#pragma unroll
        for (int h4 = 0; h4 < HID / 4; h4++) {
            const float4 w = sW2_4[j * (HID / 4) + h4];
            a2[4 * h4 + 0] = fmaf(hj, w.x, a2[4 * h4 + 0]);
            a2[4 * h4 + 1] = fmaf(hj, w.y, a2[4 * h4 + 1]);
            a2[4 * h4 + 2] = fmaf(hj, w.z, a2[4 * h4 + 2]);
            a2[4 * h4 + 3] = fmaf(hj, w.w, a2[4 * h4 + 3]);
        }
    }

    // layer 3 + eij; then gz2 in place of a2
    float e = b3v;
#pragma unroll
    for (int h4 = 0; h4 < HID / 4; h4++) {
        const float4 w = sW3_4[h4];
        float t0 = fast_tanh(a2[4 * h4 + 0]);
        float t1 = fast_tanh(a2[4 * h4 + 1]);
        float t2 = fast_tanh(a2[4 * h4 + 2]);
        float t3 = fast_tanh(a2[4 * h4 + 3]);
        e = fmaf(t0, w.x, e); e = fmaf(t1, w.y, e);
        e = fmaf(t2, w.z, e); e = fmaf(t3, w.w, e);
        a2[4 * h4 + 0] = fc * w.x * (1.0f - t0 * t0);
        a2[4 * h4 + 1] = fc * w.y * (1.0f - t1 * t1);
        a2[4 * h4 + 2] = fc * w.z * (1.0f - t2 * t2);
        a2[4 * h4 + 3] = fc * w.w * (1.0f - t3 * t3);
    }
    g_eij[p] = e;

    // gz1 in place of h1
#pragma unroll
    for (int j = 0; j < HID; j++) {
        float s = 0.0f;
#pragma unroll
        for (int h4 = 0; h4 < HID / 4; h4++) {
            const float4 w = sW2_4[j * (HID / 4) + h4];
            s = fmaf(a2[4 * h4 + 0], w.x, s);
            s = fmaf(a2[4 * h4 + 1], w.y, s);
            s = fmaf(a2[4 * h4 + 2], w.z, s);
            s = fmaf(a2[4 * h4 + 3], w.w, s);
        }
        h1[j] = s * (1.0f - h1[j] * h1[j]);
    }

    // gdesc
#pragma unroll
    for (int j = 0; j < ND; j++) {
        float s = 0.0f;
#pragma unroll
        for (int h4 = 0; h4 < HID / 4; h4++) {
            const float4 w = sW1_4[j * (HID / 4) + h4];
            s = fmaf(h1[4 * h4 + 0], w.x, s);
            s = fmaf(h1[4 * h4 + 1], w.y, s);
            s = fmaf(h1[4 * h4 + 2], w.z, s);
            s = fmaf(h1[4 * h4 + 3], w.w, s);
        }
        g_gdesc[j * P + p] = s;
    }
}

// ---------------- Kernel 3: per-atom backward -----------------------------
__global__ __launch_bounds__(256) void k_bwd_atom(const float* __restrict__ rij,
                                                  float* __restrict__ out) {
    __shared__ float su[K][3];
    __shared__ float sd_[K];
    __shared__ float sfcrik[K];
    __shared__ float sS[K][K + 1];
    __shared__ float sT[K][K + 1];
    __shared__ float sgG[K][NM];
    __shared__ float sgu[K][3];
    __shared__ float sgf[K];
    const int atom = blockIdx.x, t = threadIdx.x, base = atom * K;

    if (t < K) {
        const float x = rij[3 * (base + t) + 0];
        const float y = rij[3 * (base + t) + 1];
        const float z = rij[3 * (base + t) + 2];
        const float d = sqrtf(x * x + y * y + z * z);
        const float inv = 1.0f / fmaxf(d, 1e-12f);
        su[t][0] = x * inv; su[t][1] = y * inv; su[t][2] = z * inv;
        sd_[t] = d;
        sfcrik[t] = 0.5f + 0.5f * __cosf(POC * d);
    }
    for (int idx = t; idx < K * NM; idx += 256) {
        const int k = idx / NM, m = idx - k * NM;
        sgG[k][m] = g_gdesc[(NR + m) * P + base + k];
    }
    __syncthreads();

    // cosang into sS
    for (int idx = t; idx < K * K; idx += 256) {
        const int k = idx / K, l = idx - k * K;
        const float c = su[k][0] * su[l][0] + su[k][1] * su[l][1] + su[k][2] * su[l][2];
        sS[k][l] = (k == l) ? 0.0f : c;
    }
    __syncthreads();

    // S and T (each entry owned by exactly one thread -> in-place safe)
    for (int idx = t; idx < K * K; idx += 256) {
        const int k = idx / K, l = idx - k * K;
        const float c = sS[k][l];
        float Ss = 0.0f, Ts = 0.0f;
#pragma unroll
        for (int m = 0; m < NM; m++) {
            const float mu = -1.0f + (2.0f / 11.0f) * (float)m;
            const float df = c - mu;
            const float e2 = __expf(-4.0f * df * df);
            const float g = sgG[k][m];
            Ts = fmaf(g, e2, Ts);
            Ss = fmaf(g * df, e2, Ss);
        }
        sT[k][l] = Ts;
        sS[k][l] = (k == l) ? 0.0f : (-8.0f) * Ss;  // -2*eta = -8
    }
    __syncthreads();

    // reductions: gfcrik (wave 0) and gu (wave 1)
    if (t < K) {
        float s = 0.0f;
#pragma unroll 4
        for (int kk = 0; kk < K; kk++) s += sT[kk][t];
        sgf[t] = s;
    } else if (t >= 64 && t < 64 + K) {
        const int k = t - 64;
        const float fk = sfcrik[k];
        float gx = 0.0f, gy = 0.0f, gz = 0.0f;
#pragma unroll 4
        for (int l = 0; l < K; l++) {
            const float w = fmaf(sS[k][l], sfcrik[l], sS[l][k] * fk);
            gx = fmaf(w, su[l][0], gx);
            gy = fmaf(w, su[l][1], gy);
            gz = fmaf(w, su[l][2], gz);
        }
        sgu[k][0] = gx; sgu[k][1] = gy; sgu[k][2] = gz;
    }
    __syncthreads();

    if (t < K) {
        const float d = sd_[t];
        const float ux = su[t][0], uy = su[t][1], uz = su[t][2];
        const float invd = 1.0f / d;
        float gfc = g_eij[base + t];
        float gdR = 0.0f;
#pragma unroll
        for (int n = 0; n < NR; n++) {
            const float bn = (float)(n + 1) * POC;
            float sn, cn;
            __sincosf(bn * d, &sn, &cn);
            const float g = g_gdesc[n * P + base + t];
            gfc = fmaf(g, SQ * sn * invd, gfc);
            gdR = fmaf(g, SQ * (bn * cn - sn * invd) * invd, gdR);
        }
        float fc, dfc;
        if (d > RMIN_F) {
            float sa, ca;
            __sincosf(AFC * (d - RMIN_F), &sa, &ca);
            fc = 0.5f + 0.5f * ca;
            dfc = -0.5f * AFC * sa;
        } else { fc = 1.0f; dfc = 0.0f; }
        const float dfcrik = -0.5f * POC * __sinf(POC * d);

        const float gd = fc * gdR + gfc * dfc + sgf[t] * dfcrik;
        const float gux = sgu[t][0], guy = sgu[t][1], guz = sgu[t][2];
        const float dot = gux * ux + guy * uy + guz * uz;

        out[3 * (base + t) + 0] = fmaf(gd, ux, (gux - dot * ux) * invd);
        out[3 * (base + t) + 1] = fmaf(gd, uy, (guy - dot * uy) * invd);
        out[3 * (base + t) + 2] = fmaf(gd, uz, (guz - dot * uz) * invd);
    }
}

extern "C" void kernel_launch(void* const* d_in, const int* in_sizes, int n_in,
                              void* d_out, int out_size, void* d_ws, size_t ws_size,
                              hipStream_t stream) {
    (void)in_sizes; (void)n_in; (void)out_size; (void)d_ws; (void)ws_size;
    const float* rij = (const float*)d_in[0];
    // d_in[1] = unique_i (unused: dense K neighbors per atom)
    const float* W1 = (const float*)d_in[2];
    const float* b1 = (const float*)d_in[3];
    const float* W2 = (const float*)d_in[4];
    const float* b2 = (const float*)d_in[5];
    const float* W3 = (const float*)d_in[6];
    const float* b3 = (const float*)d_in[7];
    float* out = (float*)d_out;

    k_fwd_atom<<<NATOMS, 256, 0, stream>>>(rij);
    k_mlp<<<P / MLP_BLK, MLP_BLK, 0, stream>>>(rij, W1, b1, W2, b2, W3, b3);
    k_bwd_atom<<<NATOMS, 256, 0, stream>>>(rij, out);
}

// Round 4
// 169.338 us; speedup vs baseline: 16.5933x; 16.5933x over previous
//
#include <hip/hip_runtime.h>
#include <hip/hip_bf16.h>

#define NATOMS 2048
#define K 48
#define P (NATOMS * K)
#define NR 5
#define NM 12
#define ND 17
#define HID 64

#define PI_F 3.14159265358979f
#define CUT 3.0f
#define RMIN_F 3.5f
#define AFC (-6.28318530717959f)   /* pi/(CUT-RMIN) = pi/(-0.5) */
#define POC (PI_F / CUT)           /* pi/3 */
#define SQ 0.816496580927726f      /* sqrt(2/3) */

// Scratch in device globals (fully rewritten every call before any read).
__device__ float g_desc[ND * P];   // transposed: [feature][pair]
__device__ float g_gdesc[ND * P];  // transposed: [feature][pair]
__device__ float g_eij[P];

__device__ __forceinline__ float fast_tanh(float x) {
    float cx = fminf(fmaxf(x, -15.0f), 15.0f);
    float t = __expf(2.0f * cx);
    return (t - 1.0f) / (t + 1.0f);
}

// ---------------- Kernel 1: per-atom forward (rbf + 3-body descriptors) ---
__global__ __launch_bounds__(256) void k_fwd_atom(const float* __restrict__ rij) {
    __shared__ float su[K][3];
    __shared__ float sfcrik[K];
    __shared__ float sc[K][K + 1];
    const int atom = blockIdx.x, t = threadIdx.x, base = atom * K;

    if (t < K) {
        const float x = rij[3 * (base + t) + 0];
        const float y = rij[3 * (base + t) + 1];
        const float z = rij[3 * (base + t) + 2];
        const float d = sqrtf(x * x + y * y + z * z);
        const float inv = 1.0f / fmaxf(d, 1e-12f);
        su[t][0] = x * inv; su[t][1] = y * inv; su[t][2] = z * inv;
        sfcrik[t] = 0.5f + 0.5f * __cosf(POC * d);
        const float fc = (d > RMIN_F) ? (0.5f + 0.5f * __cosf(AFC * (d - RMIN_F))) : 1.0f;
        const float s = SQ * fc / d;
#pragma unroll
        for (int n = 0; n < NR; n++) {
            const float bn = (float)(n + 1) * POC;
            g_desc[n * P + base + t] = s * __sinf(bn * d);
        }
    }
    __syncthreads();

    for (int idx = t; idx < K * K; idx += 256) {
        const int k = idx / K, l = idx - k * K;
        const float c = su[k][0] * su[l][0] + su[k][1] * su[l][1] + su[k][2] * su[l][2];
        sc[k][l] = (k == l) ? 0.0f : c;
    }
    __syncthreads();

    for (int idx = t; idx < K * NM; idx += 256) {
        const int k = idx / NM, m = idx - k * NM;
        const float mu = -1.0f + (2.0f / 11.0f) * (float)m;
        float s = 0.0f;
#pragma unroll 4
        for (int l = 0; l < K; l++) {
            const float df = sc[k][l] - mu;
            s = fmaf(__expf(-4.0f * df * df), sfcrik[l], s);
        }
        g_desc[(NR + m) * P + base + k] = s;
    }
}

// ---------------- Kernel 2: MLP fwd+bwd, h-sliced across 4 waves ----------
// Wave w of each block owns hidden slice [16w,16w+16); lane = pair (64/block).
// Weights: wave-uniform scalar loads (readfirstlane-pinned). Activations
// cross waves via transposed LDS [h][pair] (stride 66 -> 2-way = free).
__global__ __launch_bounds__(256, 4) void k_mlp(const float* __restrict__ rij,
                                                const float* __restrict__ W1,
                                                const float* __restrict__ b1,
                                                const float* __restrict__ W2,
                                                const float* __restrict__ b2,
                                                const float* __restrict__ W3,
                                                const float* __restrict__ b3) {
    __shared__ float bufA[4 * 64 * 19];  // h1 exchange [64][66] (4224) / red [4][64][19] (4864)
    __shared__ float bufB[64 * 66];      // gz2 exchange [h][pair]

    const int t = threadIdx.x;
    const int w = t >> 6;                 // h-slice id 0..3
    const int pl = t & 63;                // pair lane
    const int base = blockIdx.x * 64;
    const int p = base + pl;
    const int h0 = __builtin_amdgcn_readfirstlane(w * 16);  // force SGPR -> s_load weights

    // ---- phase 0: layer-1 slice ----
    float h1[16];
#pragma unroll
    for (int i = 0; i < 16; i++) h1[i] = b1[h0 + i];
#pragma unroll
    for (int j = 0; j < ND; j++) {
        const float dj = g_desc[j * P + p];
#pragma unroll
        for (int i = 0; i < 16; i++) h1[i] = fmaf(dj, W1[j * HID + h0 + i], h1[i]);
    }
#pragma unroll
    for (int i = 0; i < 16; i++) {
        h1[i] = fast_tanh(h1[i]);
        bufA[(h0 + i) * 66 + pl] = h1[i];
    }
    __syncthreads();

    // fc for this lane's pair
    const float x = rij[3 * p], y = rij[3 * p + 1], z = rij[3 * p + 2];
    const float d = sqrtf(x * x + y * y + z * z);
    const float fc = (d > RMIN_F) ? (0.5f + 0.5f * __cosf(AFC * (d - RMIN_F))) : 1.0f;

    // ---- phase 1: layer-2 slice, e partial, gz2 slice ----
    float a2[16];
#pragma unroll
    for (int i = 0; i < 16; i++) a2[i] = b2[h0 + i];
#pragma unroll
    for (int hc = 0; hc < 4; hc++) {
        float hv[16];
#pragma unroll
        for (int hh = 0; hh < 16; hh++) hv[hh] = bufA[(hc * 16 + hh) * 66 + pl];
#pragma unroll
        for (int hh = 0; hh < 16; hh++) {
            const float hj = hv[hh];
#pragma unroll
            for (int i = 0; i < 16; i++)
                a2[i] = fmaf(hj, W2[(hc * 16 + hh) * HID + h0 + i], a2[i]);
        }
    }
    float e_part = 0.0f;
#pragma unroll
    for (int i = 0; i < 16; i++) {
        const float tv = fast_tanh(a2[i]);
        const float w3 = W3[h0 + i];
        e_part = fmaf(tv, w3, e_part);
        bufB[(h0 + i) * 66 + pl] = fc * w3 * (1.0f - tv * tv);  // gz2
    }
    __syncthreads();

    // ---- phase 2: gz1 slice, gdesc partials ----
    float gz1[16];
#pragma unroll
    for (int i = 0; i < 16; i++) gz1[i] = 0.0f;
#pragma unroll
    for (int hc = 0; hc < 4; hc++) {
        float gv[16];
#pragma unroll
        for (int hh = 0; hh < 16; hh++) gv[hh] = bufB[(hc * 16 + hh) * 66 + pl];
#pragma unroll
        for (int i = 0; i < 16; i++) {
            float s = 0.0f;
#pragma unroll
            for (int hh = 0; hh < 16; hh++)
                s = fmaf(gv[hh], W2[(h0 + i) * HID + hc * 16 + hh], s);
            gz1[i] += s;
        }
    }
#pragma unroll
    for (int i = 0; i < 16; i++) gz1[i] *= (1.0f - h1[i] * h1[i]);

#pragma unroll
    for (int j = 0; j < ND; j++) {
        float s = 0.0f;
#pragma unroll
        for (int i = 0; i < 16; i++) s = fmaf(gz1[i], W1[j * HID + h0 + i], s);
        bufA[(w * 64 + pl) * 19 + j] = s;   // partial gdesc
    }
    bufA[(w * 64 + pl) * 19 + 17] = e_part; // partial eij
    __syncthreads();

    // ---- phase 3: reduce partials across waves, write global ----
    const float b3v = b3[0];
    for (int idx = t; idx < 18 * 64; idx += 256) {
        const int j = idx >> 6;       // wave-uniform within each 64-lane stretch
        const int pr = idx & 63;
        float s = bufA[(0 * 64 + pr) * 19 + j] + bufA[(1 * 64 + pr) * 19 + j]
                + bufA[(2 * 64 + pr) * 19 + j] + bufA[(3 * 64 + pr) * 19 + j];
        if (j < ND) g_gdesc[j * P + base + pr] = s;
        else        g_eij[base + pr] = s + b3v;
    }
}

// ---------------- Kernel 3: per-atom backward -----------------------------
__global__ __launch_bounds__(256) void k_bwd_atom(const float* __restrict__ rij,
                                                  float* __restrict__ out) {
    __shared__ float su[K][3];
    __shared__ float sd_[K];
    __shared__ float sfcrik[K];
    __shared__ float sS[K][K + 1];
    __shared__ float sT[K][K + 1];
    __shared__ float sgG[K][NM];
    __shared__ float sgu[K][3];
    __shared__ float sgf[K];
    const int atom = blockIdx.x, t = threadIdx.x, base = atom * K;

    if (t < K) {
        const float x = rij[3 * (base + t) + 0];
        const float y = rij[3 * (base + t) + 1];
        const float z = rij[3 * (base + t) + 2];
        const float d = sqrtf(x * x + y * y + z * z);
        const float inv = 1.0f / fmaxf(d, 1e-12f);
        su[t][0] = x * inv; su[t][1] = y * inv; su[t][2] = z * inv;
        sd_[t] = d;
        sfcrik[t] = 0.5f + 0.5f * __cosf(POC * d);
    }
    for (int idx = t; idx < K * NM; idx += 256) {
        const int k = idx / NM, m = idx - k * NM;
        sgG[k][m] = g_gdesc[(NR + m) * P + base + k];
    }
    __syncthreads();

    for (int idx = t; idx < K * K; idx += 256) {
        const int k = idx / K, l = idx - k * K;
        const float c = su[k][0] * su[l][0] + su[k][1] * su[l][1] + su[k][2] * su[l][2];
        sS[k][l] = (k == l) ? 0.0f : c;
    }
    __syncthreads();

    for (int idx = t; idx < K * K; idx += 256) {
        const int k = idx / K, l = idx - k * K;
        const float c = sS[k][l];
        float Ss = 0.0f, Ts = 0.0f;
#pragma unroll
        for (int m = 0; m < NM; m++) {
            const float mu = -1.0f + (2.0f / 11.0f) * (float)m;
            const float df = c - mu;
            const float e2 = __expf(-4.0f * df * df);
            const float g = sgG[k][m];
            Ts = fmaf(g, e2, Ts);
            Ss = fmaf(g * df, e2, Ss);
        }
        sT[k][l] = Ts;
        sS[k][l] = (k == l) ? 0.0f : (-8.0f) * Ss;  // -2*eta = -8
    }
    __syncthreads();

    if (t < K) {
        float s = 0.0f;
#pragma unroll 4
        for (int kk = 0; kk < K; kk++) s += sT[kk][t];
        sgf[t] = s;
    } else if (t >= 64 && t < 64 + K) {
        const int k = t - 64;
        const float fk = sfcrik[k];
        float gx = 0.0f, gy = 0.0f, gz = 0.0f;
#pragma unroll 4
        for (int l = 0; l < K; l++) {
            const float w = fmaf(sS[k][l], sfcrik[l], sS[l][k] * fk);
            gx = fmaf(w, su[l][0], gx);
            gy = fmaf(w, su[l][1], gy);
            gz = fmaf(w, su[l][2], gz);
        }
        sgu[k][0] = gx; sgu[k][1] = gy; sgu[k][2] = gz;
    }
    __syncthreads();

    if (t < K) {
        const float d = sd_[t];
        const float ux = su[t][0], uy = su[t][1], uz = su[t][2];
        const float invd = 1.0f / d;
        float gfc = g_eij[base + t];
        float gdR = 0.0f;
#pragma unroll
        for (int n = 0; n < NR; n++) {
            const float bn = (float)(n + 1) * POC;
            float sn, cn;
            __sincosf(bn * d, &sn, &cn);
            const float g = g_gdesc[n * P + base + t];
            gfc = fmaf(g, SQ * sn * invd, gfc);
            gdR = fmaf(g, SQ * (bn * cn - sn * invd) * invd, gdR);
        }
        float fc, dfc;
        if (d > RMIN_F) {
            float sa, ca;
            __sincosf(AFC * (d - RMIN_F), &sa, &ca);
            fc = 0.5f + 0.5f * ca;
            dfc = -0.5f * AFC * sa;
        } else { fc = 1.0f; dfc = 0.0f; }
        const float dfcrik = -0.5f * POC * __sinf(POC * d);

        const float gd = fc * gdR + gfc * dfc + sgf[t] * dfcrik;
        const float gux = sgu[t][0], guy = sgu[t][1], guz = sgu[t][2];
        const float dot = gux * ux + guy * uy + guz * uz;

        out[3 * (base + t) + 0] = fmaf(gd, ux, (gux - dot * ux) * invd);
        out[3 * (base + t) + 1] = fmaf(gd, uy, (guy - dot * uy) * invd);
        out[3 * (base + t) + 2] = fmaf(gd, uz, (guz - dot * uz) * invd);
    }
}

extern "C" void kernel_launch(void* const* d_in, const int* in_sizes, int n_in,
                              void* d_out, int out_size, void* d_ws, size_t ws_size,
                              hipStream_t stream) {
    (void)in_sizes; (void)n_in; (void)out_size; (void)d_ws; (void)ws_size;
    const float* rij = (const float*)d_in[0];
    // d_in[1] = unique_i (unused: dense K neighbors per atom)
    const float* W1 = (const float*)d_in[2];
    const float* b1 = (const float*)d_in[3];
    const float* W2 = (const float*)d_in[4];
    const float* b2 = (const float*)d_in[5];
    const float* W3 = (const float*)d_in[6];
    const float* b3 = (const float*)d_in[7];
    float* out = (float*)d_out;

    k_fwd_atom<<<NATOMS, 256, 0, stream>>>(rij);
    k_mlp<<<P / 64, 256, 0, stream>>>(rij, W1, b1, W2, b2, W3, b3);
    k_bwd_atom<<<NATOMS, 256, 0, stream>>>(rij, out);
}

// Round 5
// 158.441 us; speedup vs baseline: 17.7345x; 1.0688x over previous
//
#include <hip/hip_runtime.h>
#include <hip/hip_bf16.h>

#define NATOMS 2048
#define K 48
#define P (NATOMS * K)
#define NR 5
#define NM 12
#define ND 17
#define HID 64

#define PI_F 3.14159265358979f
#define CUT 3.0f
#define RMIN_F 3.5f
#define AFC (-6.28318530717959f)   /* pi/(CUT-RMIN) = pi/(-0.5) */
#define POC (PI_F / CUT)           /* pi/3 */
#define SQ 0.816496580927726f      /* sqrt(2/3) */
#define E1C 1.45454545454545f      /* 16/11 */
#define CMC (-0.132231404958678f)  /* -16/121 */

// Scratch in device globals (fully rewritten every call before any read).
__device__ float g_desc[ND * P];   // transposed: [feature][pair]
__device__ float g_gdesc[ND * P];  // transposed: [feature][pair]
__device__ float g_eij[P];

__device__ __forceinline__ float fast_tanh(float x) {
    float cx = fminf(fmaxf(x, -15.0f), 15.0f);
    float t = __expf(2.0f * cx);
    return (t - 1.0f) / (t + 1.0f);
}

// ---------------- Kernel 1: per-atom forward (rbf + 3-body descriptors) ---
// 192 threads: exact tiling (2304 = 12*192, 576 = 3*192). Gaussian factorized:
// exp(-4(c-mu_m)^2) = E0 * E1^m * C_m  -> 2 exps + 1 mul per m (was 12 exps).
__global__ __launch_bounds__(192) void k_fwd_atom(const float* __restrict__ rij) {
    __shared__ float su[K][3];
    __shared__ float sfcrik[K];
    __shared__ float sc[K * (K + 1)];
    __shared__ float spart[4 * K * 13];  // [chunk][k][m] (stride 13: bank-safe)
    const int atom = blockIdx.x, t = threadIdx.x, base = atom * K;

    if (t < K) {
        const float x = rij[3 * (base + t) + 0];
        const float y = rij[3 * (base + t) + 1];
        const float z = rij[3 * (base + t) + 2];
        const float d = sqrtf(x * x + y * y + z * z);
        const float inv = 1.0f / fmaxf(d, 1e-12f);
        su[t][0] = x * inv; su[t][1] = y * inv; su[t][2] = z * inv;
        sfcrik[t] = 0.5f + 0.5f * __cosf(POC * d);
        const float fc = (d > RMIN_F) ? (0.5f + 0.5f * __cosf(AFC * (d - RMIN_F))) : 1.0f;
        const float s = SQ * fc / d;
#pragma unroll
        for (int n = 0; n < NR; n++) {
            const float bn = (float)(n + 1) * POC;
            g_desc[n * P + base + t] = s * __sinf(bn * d);
        }
    }
    __syncthreads();

#pragma unroll
    for (int r = 0; r < 12; r++) {
        const int idx = t + r * 192;
        const int k = idx / K, l = idx - k * K;
        const float c = su[k][0] * su[l][0] + su[k][1] * su[l][1] + su[k][2] * su[l][2];
        sc[k * (K + 1) + l] = (k == l) ? 0.0f : c;
    }
    __syncthreads();

    {
        const int k = t % K, ch = t / K;  // ch in [0,4)
        float part[NM];
#pragma unroll
        for (int m = 0; m < NM; m++) part[m] = 0.0f;
#pragma unroll
        for (int li = 0; li < 12; li++) {
            const int l = ch * 12 + li;
            const float cp1 = sc[k * (K + 1) + l] + 1.0f;
            const float e0 = __expf(-4.0f * cp1 * cp1) * sfcrik[l];
            const float e1 = __expf(E1C * cp1);
            float tm = e0;
            part[0] += tm;
#pragma unroll
            for (int m = 1; m < NM; m++) { tm *= e1; part[m] += tm; }
        }
#pragma unroll
        for (int m = 0; m < NM; m++) spart[(ch * K + k) * 13 + m] = part[m];
    }
    __syncthreads();

#pragma unroll
    for (int r = 0; r < 3; r++) {
        const int idx = t + r * 192;
        const int k = idx / NM, m = idx - k * NM;
        const float cm = __expf(CMC * (float)(m * m));
        const float s = spart[(0 * K + k) * 13 + m] + spart[(1 * K + k) * 13 + m]
                      + spart[(2 * K + k) * 13 + m] + spart[(3 * K + k) * 13 + m];
        g_desc[(NR + m) * P + base + k] = s * cm;
    }
}

// ---------------- Kernel 2: MLP fwd+bwd, h-sliced across 4 waves ----------
// bf16 LDS exchange (16 KB total) -> 6 blocks/CU fully resident; partials
// alias the exchange region (barrier-protected).
__global__ __launch_bounds__(256, 6) void k_mlp(const float* __restrict__ rij,
                                                const float* __restrict__ W1,
                                                const float* __restrict__ b1,
                                                const float* __restrict__ W2,
                                                const float* __restrict__ b2,
                                                const float* __restrict__ W3,
                                                const float* __restrict__ b3) {
    __shared__ __align__(16) __hip_bfloat16 sX[2 * 64 * 64];
    __hip_bfloat16* h1x  = sX;            // [h][pair], stride 64
    __hip_bfloat16* gz2x = sX + 64 * 64;  // [h][pair], stride 64
    __hip_bfloat16* parts = sX;           // reused: [(w*64+pl)*19 + j]

    const int t = threadIdx.x;
    const int w = t >> 6;                 // h-slice id 0..3
    const int pl = t & 63;                // pair lane
    const int base = blockIdx.x * 64;
    const int p = base + pl;
    const int h0 = __builtin_amdgcn_readfirstlane(w * 16);  // force SGPR -> s_load weights

    // ---- phase 0: layer-1 slice ----
    float h1[16];
#pragma unroll
    for (int i = 0; i < 16; i++) h1[i] = b1[h0 + i];
#pragma unroll
    for (int j = 0; j < ND; j++) {
        const float dj = g_desc[j * P + p];
#pragma unroll
        for (int i = 0; i < 16; i++) h1[i] = fmaf(dj, W1[j * HID + h0 + i], h1[i]);
    }
#pragma unroll
    for (int i = 0; i < 16; i++) {
        h1[i] = fast_tanh(h1[i]);
        h1x[(h0 + i) * 64 + pl] = __float2bfloat16(h1[i]);
    }
    __syncthreads();

    // fc for this lane's pair
    const float x = rij[3 * p], y = rij[3 * p + 1], z = rij[3 * p + 2];
    const float d = sqrtf(x * x + y * y + z * z);
    const float fc = (d > RMIN_F) ? (0.5f + 0.5f * __cosf(AFC * (d - RMIN_F))) : 1.0f;

    // ---- phase 1: layer-2 slice, e partial, gz2 slice ----
    float a2[16];
#pragma unroll
    for (int i = 0; i < 16; i++) a2[i] = b2[h0 + i];
#pragma unroll
    for (int hc = 0; hc < 4; hc++) {
        float hv[16];
#pragma unroll
        for (int hh = 0; hh < 16; hh++) hv[hh] = __bfloat162float(h1x[(hc * 16 + hh) * 64 + pl]);
#pragma unroll
        for (int hh = 0; hh < 16; hh++) {
            const float hj = hv[hh];
#pragma unroll
            for (int i = 0; i < 16; i++)
                a2[i] = fmaf(hj, W2[(hc * 16 + hh) * HID + h0 + i], a2[i]);
        }
    }
    float e_part = 0.0f;
#pragma unroll
    for (int i = 0; i < 16; i++) {
        const float tv = fast_tanh(a2[i]);
        const float w3 = W3[h0 + i];
        e_part = fmaf(tv, w3, e_part);
        gz2x[(h0 + i) * 64 + pl] = __float2bfloat16(fc * w3 * (1.0f - tv * tv));
    }
    __syncthreads();

    // ---- phase 2: gz1 slice, gdesc partials ----
    float gz1[16];
#pragma unroll
    for (int i = 0; i < 16; i++) gz1[i] = 0.0f;
#pragma unroll
    for (int hc = 0; hc < 4; hc++) {
        float gv[16];
#pragma unroll
        for (int hh = 0; hh < 16; hh++) gv[hh] = __bfloat162float(gz2x[(hc * 16 + hh) * 64 + pl]);
#pragma unroll
        for (int i = 0; i < 16; i++) {
            float s = 0.0f;
#pragma unroll
            for (int hh = 0; hh < 16; hh++)
                s = fmaf(gv[hh], W2[(h0 + i) * HID + hc * 16 + hh], s);
            gz1[i] += s;
        }
    }
#pragma unroll
    for (int i = 0; i < 16; i++) gz1[i] *= (1.0f - h1[i] * h1[i]);

    __syncthreads();  // protect exchange region before aliasing as partials

#pragma unroll
    for (int j = 0; j < ND; j++) {
        float s = 0.0f;
#pragma unroll
        for (int i = 0; i < 16; i++) s = fmaf(gz1[i], W1[j * HID + h0 + i], s);
        parts[(w * 64 + pl) * 19 + j] = __float2bfloat16(s);
    }
    parts[(w * 64 + pl) * 19 + 17] = __float2bfloat16(e_part);
    __syncthreads();

    // ---- phase 3: reduce partials across waves, write global ----
    const float b3v = b3[0];
    for (int idx = t; idx < 18 * 64; idx += 256) {
        const int j = idx >> 6;       // wave-uniform (64 | stride)
        const int pr = idx & 63;
        float s = __bfloat162float(parts[(0 * 64 + pr) * 19 + j])
                + __bfloat162float(parts[(1 * 64 + pr) * 19 + j])
                + __bfloat162float(parts[(2 * 64 + pr) * 19 + j])
                + __bfloat162float(parts[(3 * 64 + pr) * 19 + j]);
        if (j < ND) g_gdesc[j * P + base + pr] = s;
        else        g_eij[base + pr] = s + b3v;
    }
}

// ---------------- Kernel 3: per-atom backward -----------------------------
__global__ __launch_bounds__(256) void k_bwd_atom(const float* __restrict__ rij,
                                                  float* __restrict__ out) {
    __shared__ float su[K][3];
    __shared__ float sd_[K];
    __shared__ float sfcrik[K];
    __shared__ float sS[K][K + 1];
    __shared__ float sT[K][K + 1];
    __shared__ float sgG[K][NM];     // pre-multiplied by C_m
    __shared__ float sgu[K][3];
    __shared__ float sgf[K];
    const int atom = blockIdx.x, t = threadIdx.x, base = atom * K;

    if (t < K) {
        const float x = rij[3 * (base + t) + 0];
        const float y = rij[3 * (base + t) + 1];
        const float z = rij[3 * (base + t) + 2];
        const float d = sqrtf(x * x + y * y + z * z);
        const float inv = 1.0f / fmaxf(d, 1e-12f);
        su[t][0] = x * inv; su[t][1] = y * inv; su[t][2] = z * inv;
        sd_[t] = d;
        sfcrik[t] = 0.5f + 0.5f * __cosf(POC * d);
    }
    for (int idx = t; idx < K * NM; idx += 256) {
        const int k = idx / NM, m = idx - k * NM;
        sgG[k][m] = g_gdesc[(NR + m) * P + base + k] * __expf(CMC * (float)(m * m));
    }
    __syncthreads();

    for (int idx = t; idx < K * K; idx += 256) {
        const int k = idx / K, l = idx - k * K;
        const float c = su[k][0] * su[l][0] + su[k][1] * su[l][1] + su[k][2] * su[l][2];
        sS[k][l] = (k == l) ? 0.0f : c;
    }
    __syncthreads();

    // S and T via factorized Gaussian: q_m = gGC*E0*E1^m; T=sum q;
    // S' = sum q*(c-mu_m) = cp1*T - (2/11)*U, U = sum m*q.
    for (int idx = t; idx < K * K; idx += 256) {
        const int k = idx / K, l = idx - k * K;
        const float cp1 = sS[k][l] + 1.0f;
        const float e0 = __expf(-4.0f * cp1 * cp1);
        const float e1 = __expf(E1C * cp1);
        float tm = e0;
        float T = sgG[k][0] * tm, U = 0.0f;
#pragma unroll
        for (int m = 1; m < NM; m++) {
            tm *= e1;
            const float q = sgG[k][m] * tm;
            T += q;
            U = fmaf((float)m, q, U);
        }
        const float Sp = cp1 * T - (2.0f / 11.0f) * U;
        sT[k][l] = T;
        sS[k][l] = (k == l) ? 0.0f : (-8.0f) * Sp;
    }
    __syncthreads();

    if (t < K) {
        float s = 0.0f;
#pragma unroll 4
        for (int kk = 0; kk < K; kk++) s += sT[kk][t];
        sgf[t] = s;
    } else if (t >= 64 && t < 64 + K) {
        const int k = t - 64;
        const float fk = sfcrik[k];
        float gx = 0.0f, gy = 0.0f, gz = 0.0f;
#pragma unroll 4
        for (int l = 0; l < K; l++) {
            const float w = fmaf(sS[k][l], sfcrik[l], sS[l][k] * fk);
            gx = fmaf(w, su[l][0], gx);
            gy = fmaf(w, su[l][1], gy);
            gz = fmaf(w, su[l][2], gz);
        }
        sgu[k][0] = gx; sgu[k][1] = gy; sgu[k][2] = gz;
    }
    __syncthreads();

    if (t < K) {
        const float d = sd_[t];
        const float ux = su[t][0], uy = su[t][1], uz = su[t][2];
        const float invd = 1.0f / d;
        float gfc = g_eij[base + t];
        float gdR = 0.0f;
#pragma unroll
        for (int n = 0; n < NR; n++) {
            const float bn = (float)(n + 1) * POC;
            float sn, cn;
            __sincosf(bn * d, &sn, &cn);
            const float g = g_gdesc[n * P + base + t];
            gfc = fmaf(g, SQ * sn * invd, gfc);
            gdR = fmaf(g, SQ * (bn * cn - sn * invd) * invd, gdR);
        }
        float fc, dfc;
        if (d > RMIN_F) {
            float sa, ca;
            __sincosf(AFC * (d - RMIN_F), &sa, &ca);
            fc = 0.5f + 0.5f * ca;
            dfc = -0.5f * AFC * sa;
        } else { fc = 1.0f; dfc = 0.0f; }
        const float dfcrik = -0.5f * POC * __sinf(POC * d);

        const float gd = fc * gdR + gfc * dfc + sgf[t] * dfcrik;
        const float gux = sgu[t][0], guy = sgu[t][1], guz = sgu[t][2];
        const float dot = gux * ux + guy * uy + guz * uz;

        out[3 * (base + t) + 0] = fmaf(gd, ux, (gux - dot * ux) * invd);
        out[3 * (base + t) + 1] = fmaf(gd, uy, (guy - dot * uy) * invd);
        out[3 * (base + t) + 2] = fmaf(gd, uz, (guz - dot * uz) * invd);
    }
}

extern "C" void kernel_launch(void* const* d_in, const int* in_sizes, int n_in,
                              void* d_out, int out_size, void* d_ws, size_t ws_size,
                              hipStream_t stream) {
    (void)in_sizes; (void)n_in; (void)out_size; (void)d_ws; (void)ws_size;
    const float* rij = (const float*)d_in[0];
    // d_in[1] = unique_i (unused: dense K neighbors per atom)
    const float* W1 = (const float*)d_in[2];
    const float* b1 = (const float*)d_in[3];
    const float* W2 = (const float*)d_in[4];
    const float* b2 = (const float*)d_in[5];
    const float* W3 = (const float*)d_in[6];
    const float* b3 = (const float*)d_in[7];
    float* out = (float*)d_out;

    k_fwd_atom<<<NATOMS, 192, 0, stream>>>(rij);
    k_mlp<<<P / 64, 256, 0, stream>>>(rij, W1, b1, W2, b2, W3, b3);
    k_bwd_atom<<<NATOMS, 256, 0, stream>>>(rij, out);
}

// Round 6
// 123.804 us; speedup vs baseline: 22.6962x; 1.2798x over previous
//
#include <hip/hip_runtime.h>
#include <hip/hip_bf16.h>

#define NATOMS 2048
#define K 48
#define P (NATOMS * K)
#define NR 5
#define NM 12
#define ND 17
#define HID 64

#define PI_F 3.14159265358979f
#define CUT 3.0f
#define RMIN_F 3.5f
#define AFC (-6.28318530717959f)   /* pi/(CUT-RMIN) = pi/(-0.5) */
#define POC (PI_F / CUT)           /* pi/3 */
#define SQ 0.816496580927726f      /* sqrt(2/3) */
#define E1C 1.45454545454545f      /* 16/11 */
#define CMC (-0.132231404958678f)  /* -16/121 */

// Scratch in device globals (fully rewritten every call before any read).
__device__ unsigned short g_desc[P * 32];  // bf16 bits, pair-major [p][32] (cols 17..31 = 0)
__device__ float g_gdesc[P * 20];          // pair-major [p][20]: 0..16 = gdesc, 17 = eij

using frag_ab = __attribute__((ext_vector_type(8))) short;
using frag_cd = __attribute__((ext_vector_type(4))) float;

__device__ __forceinline__ float fast_tanh(float x) {
    float cx = fminf(fmaxf(x, -15.0f), 15.0f);
    float t = __expf(2.0f * cx);
    return (t - 1.0f) / (t + 1.0f);
}

__device__ __forceinline__ unsigned short f2bs(float x) {
    __hip_bfloat16 b = __float2bfloat16(x);
    return __builtin_bit_cast(unsigned short, b);
}

// ---------------- Kernel 1: per-atom forward (rbf + 3-body descriptors) ---
// Gaussian factorized: exp(-4(c-mu_m)^2) = E0 * E1^m * C_m.
// Output: bf16 desc [p][32], written coalesced via LDS tile.
__global__ __launch_bounds__(192) void k_fwd_atom(const float* __restrict__ rij) {
    __shared__ float su[K][3];
    __shared__ float sfcrik[K];
    __shared__ float sc[K * (K + 1)];
    __shared__ float spart[4 * K * 13];
    __shared__ __align__(16) unsigned short sOut[K][32];
    const int atom = blockIdx.x, t = threadIdx.x, base = atom * K;

    if (t < K) {
        const float x = rij[3 * (base + t) + 0];
        const float y = rij[3 * (base + t) + 1];
        const float z = rij[3 * (base + t) + 2];
        const float d = sqrtf(x * x + y * y + z * z);
        const float inv = 1.0f / fmaxf(d, 1e-12f);
        su[t][0] = x * inv; su[t][1] = y * inv; su[t][2] = z * inv;
        sfcrik[t] = 0.5f + 0.5f * __cosf(POC * d);
        const float fc = (d > RMIN_F) ? (0.5f + 0.5f * __cosf(AFC * (d - RMIN_F))) : 1.0f;
        const float s = SQ * fc / d;
#pragma unroll
        for (int n = 0; n < NR; n++) {
            const float bn = (float)(n + 1) * POC;
            sOut[t][n] = f2bs(s * __sinf(bn * d));
        }
#pragma unroll
        for (int c = ND; c < 32; c++) sOut[t][c] = 0;  // K-pad for MFMA
    }
    __syncthreads();

#pragma unroll
    for (int r = 0; r < 12; r++) {
        const int idx = t + r * 192;
        const int k = idx / K, l = idx - k * K;
        const float c = su[k][0] * su[l][0] + su[k][1] * su[l][1] + su[k][2] * su[l][2];
        sc[k * (K + 1) + l] = (k == l) ? 0.0f : c;
    }
    __syncthreads();

    {
        const int k = t % K, ch = t / K;  // ch in [0,4)
        float part[NM];
#pragma unroll
        for (int m = 0; m < NM; m++) part[m] = 0.0f;
#pragma unroll
        for (int li = 0; li < 12; li++) {
            const int l = ch * 12 + li;
            const float cp1 = sc[k * (K + 1) + l] + 1.0f;
            const float e0 = __expf(-4.0f * cp1 * cp1) * sfcrik[l];
            const float e1 = __expf(E1C * cp1);
            float tm = e0;
            part[0] += tm;
#pragma unroll
            for (int m = 1; m < NM; m++) { tm *= e1; part[m] += tm; }
        }
#pragma unroll
        for (int m = 0; m < NM; m++) spart[(ch * K + k) * 13 + m] = part[m];
    }
    __syncthreads();

#pragma unroll
    for (int r = 0; r < 3; r++) {
        const int idx = t + r * 192;
        const int k = idx / NM, m = idx - k * NM;
        const float cm = __expf(CMC * (float)(m * m));
        const float s = spart[(0 * K + k) * 13 + m] + spart[(1 * K + k) * 13 + m]
                      + spart[(2 * K + k) * 13 + m] + spart[(3 * K + k) * 13 + m];
        sOut[k][NR + m] = f2bs(s * cm);
    }
    __syncthreads();

    // coalesced copy-out: 48 rows x 4 chunks of 16B = 192 threads
    {
        const int r = t >> 2, c = (t & 3) * 8;
        *(uint4*)&g_desc[(base + r) * 32 + c] = *(const uint4*)&sOut[r][c];
    }
}

// ---------------- Kernel 2: MFMA MLP fwd+bwd ------------------------------
// 64 pairs/block, 4 waves; wave w owns pair rows [16w,16w+16). All per-wave
// dataflow (h1/gz2/gz1 rows) is wave-private -> single barrier after staging.
// A-frag: lane holds A[m=lane&15][k=quad*8+j]; B-frag: B[k=quad*8+j][n=lane&15]
// staged n-major. C: col=lane&15, row=quad*4+reg.
#define LW1 40   // short-stride for desc/W1T rows (32 pad 40 -> 80B, 16-aligned)
#define LW2 72   // short-stride for 64-wide rows (144B, 16-aligned)
#define O_DESC 0          // 64*40
#define O_W1T  2560       // 64*40
#define O_W2T  5120       // 64*72
#define O_W2R  9728       // 64*72
#define O_W1R  14336      // 32*72
#define O_H1   16640      // 64*72  (aliased: gz1 written here in bwd1)
#define O_GZ2  21248      // 64*72
#define SM_SHORTS 25856

__global__ __launch_bounds__(256) void k_mlp(const float* __restrict__ rij,
                                             const float* __restrict__ W1,
                                             const float* __restrict__ b1,
                                             const float* __restrict__ W2,
                                             const float* __restrict__ b2,
                                             const float* __restrict__ W3,
                                             const float* __restrict__ b3) {
    __shared__ __align__(16) short sm[SM_SHORTS];
    __shared__ float sFc[64], sB1[64], sB2[64], sW3[64];

    const int t = threadIdx.x;
    const int base = blockIdx.x * 64;

    // ---- stage ----
    if (t < 64) {
        const int p = base + t;
        const float x = rij[3 * p], y = rij[3 * p + 1], z = rij[3 * p + 2];
        const float d = sqrtf(x * x + y * y + z * z);
        sFc[t] = (d > RMIN_F) ? (0.5f + 0.5f * __cosf(AFC * (d - RMIN_F))) : 1.0f;
        sB1[t] = b1[t]; sB2[t] = b2[t]; sW3[t] = W3[t];
    }
    {   // desc tile: 64 rows x 32 shorts, one 16B chunk per thread
        const int r = t >> 2, c = (t & 3) * 8;
        *(uint4*)&sm[O_DESC + r * LW1 + c] = *(const uint4*)&g_desc[(base + r) * 32 + c];
    }
    for (int i = t; i < 64 * 32; i += 256) {         // W1T[n=h][k=j], zero-pad k>=17
        const int n = i >> 5, k = i & 31;
        sm[O_W1T + n * LW1 + k] = (k < ND) ? (short)f2bs(W1[k * HID + n]) : (short)0;
    }
    for (int i = t; i < 64 * 64; i += 256) {         // W2T[n=h2][k=h1]
        const int n = i >> 6, k = i & 63;
        sm[O_W2T + n * LW2 + k] = (short)f2bs(W2[k * HID + n]);
    }
    for (int i = t; i < 64 * 64; i += 256) {         // W2R[n=h1][k=h2] (row-major copy)
        const int n = i >> 6, k = i & 63;
        sm[O_W2R + n * LW2 + k] = (short)f2bs(W2[n * HID + k]);
    }
    for (int i = t; i < 32 * 64; i += 256) {         // W1R[n=j][k=h1], zero-pad n>=17
        const int n = i >> 6, k = i & 63;
        sm[O_W1R + n * LW2 + k] = (n < ND) ? (short)f2bs(W1[n * HID + k]) : (short)0;
    }
    __syncthreads();

    const int w = t >> 6, lane = t & 63, quad = lane >> 4, lm = lane & 15;
    const int mrow = w * 16;

    // ---- fwd1: h1 = tanh(desc @ W1 + b1) ----
    float t1[16];
    {
        const frag_ab a = *(const frag_ab*)&sm[O_DESC + (mrow + lm) * LW1 + quad * 8];
#pragma unroll
        for (int nt = 0; nt < 4; nt++) {
            const frag_ab bf = *(const frag_ab*)&sm[O_W1T + (nt * 16 + lm) * LW1 + quad * 8];
            const float bias = sB1[nt * 16 + lm];
            frag_cd acc = {bias, bias, bias, bias};
            acc = __builtin_amdgcn_mfma_f32_16x16x32_bf16(a, bf, acc, 0, 0, 0);
#pragma unroll
            for (int r = 0; r < 4; r++) {
                const float tv = fast_tanh(acc[r]);
                t1[nt * 4 + r] = tv;
                sm[O_H1 + (mrow + quad * 4 + r) * LW2 + nt * 16 + lm] = (short)f2bs(tv);
            }
        }
    }

    // ---- fwd2: t2 = tanh(h1 @ W2 + b2); eij; gz2 = fc*W3*(1-t2^2) ----
    float fcr[4];
#pragma unroll
    for (int r = 0; r < 4; r++) fcr[r] = sFc[mrow + quad * 4 + r];
    {
        const frag_ab a0 = *(const frag_ab*)&sm[O_H1 + (mrow + lm) * LW2 + quad * 8];
        const frag_ab a1 = *(const frag_ab*)&sm[O_H1 + (mrow + lm) * LW2 + 32 + quad * 8];
        float er[4] = {0.0f, 0.0f, 0.0f, 0.0f};
#pragma unroll
        for (int nt = 0; nt < 4; nt++) {
            const int n = nt * 16 + lm;
            const frag_ab b0 = *(const frag_ab*)&sm[O_W2T + n * LW2 + quad * 8];
            const frag_ab b1f = *(const frag_ab*)&sm[O_W2T + n * LW2 + 32 + quad * 8];
            const float bias = sB2[n];
            frag_cd acc = {bias, bias, bias, bias};
            acc = __builtin_amdgcn_mfma_f32_16x16x32_bf16(a0, b0, acc, 0, 0, 0);
            acc = __builtin_amdgcn_mfma_f32_16x16x32_bf16(a1, b1f, acc, 0, 0, 0);
            const float w3n = sW3[n];
#pragma unroll
            for (int r = 0; r < 4; r++) {
                const float tv = fast_tanh(acc[r]);
                er[r] = fmaf(tv, w3n, er[r]);
                sm[O_GZ2 + (mrow + quad * 4 + r) * LW2 + n] =
                    (short)f2bs(fcr[r] * w3n * (1.0f - tv * tv));
            }
        }
#pragma unroll
        for (int off = 1; off < 16; off <<= 1) {
#pragma unroll
            for (int r = 0; r < 4; r++) er[r] += __shfl_xor(er[r], off, 64);
        }
        if (lm == 0) {
            const float b3v = b3[0];
#pragma unroll
            for (int r = 0; r < 4; r++)
                g_gdesc[(base + mrow + quad * 4 + r) * 20 + 17] = er[r] + b3v;
        }
    }

    // ---- bwd1: gz1 = (gz2 @ W2^T) * (1-h1^2) -> overwrite O_H1 ----
    {
        const frag_ab a0 = *(const frag_ab*)&sm[O_GZ2 + (mrow + lm) * LW2 + quad * 8];
        const frag_ab a1 = *(const frag_ab*)&sm[O_GZ2 + (mrow + lm) * LW2 + 32 + quad * 8];
#pragma unroll
        for (int nt = 0; nt < 4; nt++) {
            const int n = nt * 16 + lm;
            const frag_ab b0 = *(const frag_ab*)&sm[O_W2R + n * LW2 + quad * 8];
            const frag_ab b1f = *(const frag_ab*)&sm[O_W2R + n * LW2 + 32 + quad * 8];
            frag_cd acc = {0.0f, 0.0f, 0.0f, 0.0f};
            acc = __builtin_amdgcn_mfma_f32_16x16x32_bf16(a0, b0, acc, 0, 0, 0);
            acc = __builtin_amdgcn_mfma_f32_16x16x32_bf16(a1, b1f, acc, 0, 0, 0);
#pragma unroll
            for (int r = 0; r < 4; r++) {
                const float g = acc[r] * (1.0f - t1[nt * 4 + r] * t1[nt * 4 + r]);
                sm[O_H1 + (mrow + quad * 4 + r) * LW2 + n] = (short)f2bs(g);
            }
        }
    }

    // ---- bwd2: gdesc = gz1 @ W1^T ----
    {
        const frag_ab a0 = *(const frag_ab*)&sm[O_H1 + (mrow + lm) * LW2 + quad * 8];
        const frag_ab a1 = *(const frag_ab*)&sm[O_H1 + (mrow + lm) * LW2 + 32 + quad * 8];
#pragma unroll
        for (int nt = 0; nt < 2; nt++) {
            const int n = nt * 16 + lm;
            const frag_ab b0 = *(const frag_ab*)&sm[O_W1R + n * LW2 + quad * 8];
            const frag_ab b1f = *(const frag_ab*)&sm[O_W1R + n * LW2 + 32 + quad * 8];
            frag_cd acc = {0.0f, 0.0f, 0.0f, 0.0f};
            acc = __builtin_amdgcn_mfma_f32_16x16x32_bf16(a0, b0, acc, 0, 0, 0);
            acc = __builtin_amdgcn_mfma_f32_16x16x32_bf16(a1, b1f, acc, 0, 0, 0);
            if (n < ND) {
#pragma unroll
                for (int r = 0; r < 4; r++)
                    g_gdesc[(base + mrow + quad * 4 + r) * 20 + n] = acc[r];
            }
        }
    }
}

// ---------------- Kernel 3: per-atom backward -----------------------------
__global__ __launch_bounds__(256) void k_bwd_atom(const float* __restrict__ rij,
                                                  float* __restrict__ out) {
    __shared__ float su[K][3];
    __shared__ float sd_[K];
    __shared__ float sfcrik[K];
    __shared__ float sS[K][K + 1];
    __shared__ float sT[K][K + 1];
    __shared__ float sgG[K][NM];     // pre-multiplied by C_m
    __shared__ float sgu[K][3];
    __shared__ float sgf[K];
    const int atom = blockIdx.x, t = threadIdx.x, base = atom * K;

    if (t < K) {
        const float x = rij[3 * (base + t) + 0];
        const float y = rij[3 * (base + t) + 1];
        const float z = rij[3 * (base + t) + 2];
        const float d = sqrtf(x * x + y * y + z * z);
        const float inv = 1.0f / fmaxf(d, 1e-12f);
        su[t][0] = x * inv; su[t][1] = y * inv; su[t][2] = z * inv;
        sd_[t] = d;
        sfcrik[t] = 0.5f + 0.5f * __cosf(POC * d);
    }
    for (int idx = t; idx < K * NM; idx += 256) {
        const int k = idx / NM, m = idx - k * NM;
        sgG[k][m] = g_gdesc[(base + k) * 20 + NR + m] * __expf(CMC * (float)(m * m));
    }
    __syncthreads();

    for (int idx = t; idx < K * K; idx += 256) {
        const int k = idx / K, l = idx - k * K;
        const float c = su[k][0] * su[l][0] + su[k][1] * su[l][1] + su[k][2] * su[l][2];
        sS[k][l] = (k == l) ? 0.0f : c;
    }
    __syncthreads();

    // q_m = gGC*E0*E1^m; T=sum q; S' = cp1*T - (2/11)*sum(m*q)
    for (int idx = t; idx < K * K; idx += 256) {
        const int k = idx / K, l = idx - k * K;
        const float cp1 = sS[k][l] + 1.0f;
        const float e0 = __expf(-4.0f * cp1 * cp1);
        const float e1 = __expf(E1C * cp1);
        float tm = e0;
        float T = sgG[k][0] * tm, U = 0.0f;
#pragma unroll
        for (int m = 1; m < NM; m++) {
            tm *= e1;
            const float q = sgG[k][m] * tm;
            T += q;
            U = fmaf((float)m, q, U);
        }
        const float Sp = cp1 * T - (2.0f / 11.0f) * U;
        sT[k][l] = T;
        sS[k][l] = (k == l) ? 0.0f : (-8.0f) * Sp;
    }
    __syncthreads();

    if (t < K) {
        float s = 0.0f;
#pragma unroll 4
        for (int kk = 0; kk < K; kk++) s += sT[kk][t];
        sgf[t] = s;
    } else if (t >= 64 && t < 64 + K) {
        const int k = t - 64;
        const float fk = sfcrik[k];
        float gx = 0.0f, gy = 0.0f, gz = 0.0f;
#pragma unroll 4
        for (int l = 0; l < K; l++) {
            const float w = fmaf(sS[k][l], sfcrik[l], sS[l][k] * fk);
            gx = fmaf(w, su[l][0], gx);
            gy = fmaf(w, su[l][1], gy);
            gz = fmaf(w, su[l][2], gz);
        }
        sgu[k][0] = gx; sgu[k][1] = gy; sgu[k][2] = gz;
    }
    __syncthreads();

    if (t < K) {
        const float d = sd_[t];
        const float ux = su[t][0], uy = su[t][1], uz = su[t][2];
        const float invd = 1.0f / d;
        float gfc = g_gdesc[(base + t) * 20 + 17];
        float gdR = 0.0f;
#pragma unroll
        for (int n = 0; n < NR; n++) {
            const float bn = (float)(n + 1) * POC;
            float sn, cn;
            __sincosf(bn * d, &sn, &cn);
            const float g = g_gdesc[(base + t) * 20 + n];
            gfc = fmaf(g, SQ * sn * invd, gfc);
            gdR = fmaf(g, SQ * (bn * cn - sn * invd) * invd, gdR);
        }
        float fc, dfc;
        if (d > RMIN_F) {
            float sa, ca;
            __sincosf(AFC * (d - RMIN_F), &sa, &ca);
            fc = 0.5f + 0.5f * ca;
            dfc = -0.5f * AFC * sa;
        } else { fc = 1.0f; dfc = 0.0f; }
        const float dfcrik = -0.5f * POC * __sinf(POC * d);

        const float gd = fc * gdR + gfc * dfc + sgf[t] * dfcrik;
        const float gux = sgu[t][0], guy = sgu[t][1], guz = sgu[t][2];
        const float dot = gux * ux + guy * uy + guz * uz;

        out[3 * (base + t) + 0] = fmaf(gd, ux, (gux - dot * ux) * invd);
        out[3 * (base + t) + 1] = fmaf(gd, uy, (guy - dot * uy) * invd);
        out[3 * (base + t) + 2] = fmaf(gd, uz, (guz - dot * uz) * invd);
    }
}

extern "C" void kernel_launch(void* const* d_in, const int* in_sizes, int n_in,
                              void* d_out, int out_size, void* d_ws, size_t ws_size,
                              hipStream_t stream) {
    (void)in_sizes; (void)n_in; (void)out_size; (void)d_ws; (void)ws_size;
    const float* rij = (const float*)d_in[0];
    // d_in[1] = unique_i (unused: dense K neighbors per atom)
    const float* W1 = (const float*)d_in[2];
    const float* b1 = (const float*)d_in[3];
    const float* W2 = (const float*)d_in[4];
    const float* b2 = (const float*)d_in[5];
    const float* W3 = (const float*)d_in[6];
    const float* b3 = (const float*)d_in[7];
    float* out = (float*)d_out;

    k_fwd_atom<<<NATOMS, 192, 0, stream>>>(rij);
    k_mlp<<<P / 64, 256, 0, stream>>>(rij, W1, b1, W2, b2, W3, b3);
    k_bwd_atom<<<NATOMS, 256, 0, stream>>>(rij, out);
}

// Round 7
// 111.787 us; speedup vs baseline: 25.1361x; 1.1075x over previous
//
#include <hip/hip_runtime.h>
#include <hip/hip_bf16.h>

#define NATOMS 2048
#define K 48
#define P (NATOMS * K)
#define NR 5
#define NM 12
#define ND 17
#define HID 64

#define PI_F 3.14159265358979f
#define CUT 3.0f
#define RMIN_F 3.5f
#define AFC (-6.28318530717959f)   /* pi/(CUT-RMIN) = pi/(-0.5) */
#define POC (PI_F / CUT)           /* pi/3 */
#define SQ 0.816496580927726f      /* sqrt(2/3) */
#define E1C 1.45454545454545f      /* 16/11 */
#define CMC (-0.132231404958678f)  /* -16/121 */

// Scratch in device globals (fully rewritten every call before any read).
__device__ unsigned short g_desc[P * 32];  // bf16 bits, pair-major [p][32] (cols 17..31 = 0)
__device__ float g_gdesc[P * 20];          // pair-major [p][20]: 0..16 = gdesc, 17 = eij
// Packed bf16 weight layouts (built once per launch by k_prep):
__device__ unsigned short g_w1t[64 * 32];  // [n=h][k=j]  (k>=17 zero)
__device__ unsigned short g_w2t[64 * 64];  // [n=h2][k=h1]
__device__ unsigned short g_w2r[64 * 64];  // [n=h1][k=h2]
__device__ unsigned short g_w1r[32 * 64];  // [n=j][k=h]  (n>=17 zero)

using frag_ab = __attribute__((ext_vector_type(8))) short;
using frag_cd = __attribute__((ext_vector_type(4))) float;

__device__ __forceinline__ float fast_tanh(float x) {
    float cx = fminf(fmaxf(x, -15.0f), 15.0f);
    float t = __expf(2.0f * cx);
    return (t - 1.0f) / (t + 1.0f);
}

__device__ __forceinline__ unsigned short f2bs(float x) {
    __hip_bfloat16 b = __float2bfloat16(x);
    return __builtin_bit_cast(unsigned short, b);
}

// ---------------- Kernel 0: pack weights into MFMA-ready bf16 layouts -----
__global__ __launch_bounds__(256) void k_prep(const float* __restrict__ W1,
                                              const float* __restrict__ W2) {
    const int i = blockIdx.x * 256 + threadIdx.x;  // grid covers 12288
    if (i < 2048) {                                   // W1T[n][k]
        const int n = i >> 5, k = i & 31;
        g_w1t[i] = (k < ND) ? f2bs(W1[k * HID + n]) : (unsigned short)0;
    } else if (i < 2048 + 4096) {                     // W2T[n][k]
        const int j = i - 2048, n = j >> 6, k = j & 63;
        g_w2t[j] = f2bs(W2[k * HID + n]);
    } else if (i < 2048 + 8192) {                     // W2R[n][k]
        const int j = i - (2048 + 4096);
        g_w2r[j] = f2bs(W2[j]);
    } else if (i < 2048 + 8192 + 2048) {              // W1R[n][k]
        const int j = i - (2048 + 8192), n = j >> 6;
        g_w1r[j] = (n < ND) ? f2bs(W1[j]) : (unsigned short)0;
    }
}

// ---------------- Kernel 1: per-atom forward (rbf + 3-body descriptors) ---
__global__ __launch_bounds__(192) void k_fwd_atom(const float* __restrict__ rij) {
    __shared__ float su[K][3];
    __shared__ float sfcrik[K];
    __shared__ float sc[K * (K + 1)];
    __shared__ float spart[4 * K * 13];
    __shared__ __align__(16) unsigned short sOut[K][32];
    const int atom = blockIdx.x, t = threadIdx.x, base = atom * K;

    if (t < K) {
        const float x = rij[3 * (base + t) + 0];
        const float y = rij[3 * (base + t) + 1];
        const float z = rij[3 * (base + t) + 2];
        const float d = sqrtf(x * x + y * y + z * z);
        const float inv = 1.0f / fmaxf(d, 1e-12f);
        su[t][0] = x * inv; su[t][1] = y * inv; su[t][2] = z * inv;
        sfcrik[t] = 0.5f + 0.5f * __cosf(POC * d);
        const float fc = (d > RMIN_F) ? (0.5f + 0.5f * __cosf(AFC * (d - RMIN_F))) : 1.0f;
        const float s = SQ * fc / d;
#pragma unroll
        for (int n = 0; n < NR; n++) {
            const float bn = (float)(n + 1) * POC;
            sOut[t][n] = f2bs(s * __sinf(bn * d));
        }
#pragma unroll
        for (int c = ND; c < 32; c++) sOut[t][c] = 0;  // K-pad for MFMA
    }
    __syncthreads();

#pragma unroll
    for (int r = 0; r < 12; r++) {
        const int idx = t + r * 192;
        const int k = idx / K, l = idx - k * K;
        const float c = su[k][0] * su[l][0] + su[k][1] * su[l][1] + su[k][2] * su[l][2];
        sc[k * (K + 1) + l] = (k == l) ? 0.0f : c;
    }
    __syncthreads();

    {
        const int k = t % K, ch = t / K;  // ch in [0,4)
        float part[NM];
#pragma unroll
        for (int m = 0; m < NM; m++) part[m] = 0.0f;
#pragma unroll
        for (int li = 0; li < 12; li++) {
            const int l = ch * 12 + li;
            const float cp1 = sc[k * (K + 1) + l] + 1.0f;
            const float e0 = __expf(-4.0f * cp1 * cp1) * sfcrik[l];
            const float e1 = __expf(E1C * cp1);
            float tm = e0;
            part[0] += tm;
#pragma unroll
            for (int m = 1; m < NM; m++) { tm *= e1; part[m] += tm; }
        }
#pragma unroll
        for (int m = 0; m < NM; m++) spart[(ch * K + k) * 13 + m] = part[m];
    }
    __syncthreads();

#pragma unroll
    for (int r = 0; r < 3; r++) {
        const int idx = t + r * 192;
        const int k = idx / NM, m = idx - k * NM;
        const float cm = __expf(CMC * (float)(m * m));
        const float s = spart[(0 * K + k) * 13 + m] + spart[(1 * K + k) * 13 + m]
                      + spart[(2 * K + k) * 13 + m] + spart[(3 * K + k) * 13 + m];
        sOut[k][NR + m] = f2bs(s * cm);
    }
    __syncthreads();

    {
        const int r = t >> 2, c = (t & 3) * 8;
        *(uint4*)&g_desc[(base + r) * 32 + c] = *(const uint4*)&sOut[r][c];
    }
}

// ---------------- Kernel 2: MFMA MLP fwd+bwd ------------------------------
// Weight staging = coalesced uint4 copies from packed globals (k_prep).
#define LW1 40   // short-stride for desc/W1T rows
#define LW2 72   // short-stride for 64-wide rows
#define O_DESC 0          // 64*40
#define O_W1T  2560       // 64*40
#define O_W2T  5120       // 64*72
#define O_W2R  9728       // 64*72
#define O_W1R  14336      // 32*72
#define O_H1   16640      // 64*72  (aliased: gz1 written here in bwd1)
#define O_GZ2  21248      // 64*72
#define SM_SHORTS 25856

__global__ __launch_bounds__(256) void k_mlp(const float* __restrict__ rij,
                                             const float* __restrict__ b1,
                                             const float* __restrict__ b2,
                                             const float* __restrict__ W3,
                                             const float* __restrict__ b3) {
    __shared__ __align__(16) short sm[SM_SHORTS];
    __shared__ float sFc[64], sB1[64], sB2[64], sW3[64];

    const int t = threadIdx.x;
    const int base = blockIdx.x * 64;

    // ---- stage (all coalesced) ----
    if (t < 64) {
        const int p = base + t;
        const float x = rij[3 * p], y = rij[3 * p + 1], z = rij[3 * p + 2];
        const float d = sqrtf(x * x + y * y + z * z);
        sFc[t] = (d > RMIN_F) ? (0.5f + 0.5f * __cosf(AFC * (d - RMIN_F))) : 1.0f;
        sB1[t] = b1[t]; sB2[t] = b2[t]; sW3[t] = W3[t];
    }
    {   // desc tile: 64 rows x 32 shorts
        const int r = t >> 2, c = (t & 3) * 8;
        *(uint4*)&sm[O_DESC + r * LW1 + c] = *(const uint4*)&g_desc[(base + r) * 32 + c];
    }
    {   // W1T: 64 rows x 4 chunks = 256 uint4 (one per thread)
        const int n = t >> 2, c = (t & 3) * 8;
        *(uint4*)&sm[O_W1T + n * LW1 + c] = *(const uint4*)&g_w1t[n * 32 + c];
    }
#pragma unroll
    for (int rr = 0; rr < 2; rr++) {  // W2T: 512 uint4
        const int i = t + rr * 256, n = i >> 3, c = (i & 7) * 8;
        *(uint4*)&sm[O_W2T + n * LW2 + c] = *(const uint4*)&g_w2t[n * 64 + c];
    }
#pragma unroll
    for (int rr = 0; rr < 2; rr++) {  // W2R: 512 uint4
        const int i = t + rr * 256, n = i >> 3, c = (i & 7) * 8;
        *(uint4*)&sm[O_W2R + n * LW2 + c] = *(const uint4*)&g_w2r[n * 64 + c];
    }
    {   // W1R: 32 rows x 8 chunks = 256 uint4
        const int n = t >> 3, c = (t & 7) * 8;
        *(uint4*)&sm[O_W1R + n * LW2 + c] = *(const uint4*)&g_w1r[n * 64 + c];
    }
    __syncthreads();

    const int w = t >> 6, lane = t & 63, quad = lane >> 4, lm = lane & 15;
    const int mrow = w * 16;

    // ---- fwd1: h1 = tanh(desc @ W1 + b1) ----
    float t1[16];
    {
        const frag_ab a = *(const frag_ab*)&sm[O_DESC + (mrow + lm) * LW1 + quad * 8];
#pragma unroll
        for (int nt = 0; nt < 4; nt++) {
            const frag_ab bf = *(const frag_ab*)&sm[O_W1T + (nt * 16 + lm) * LW1 + quad * 8];
            const float bias = sB1[nt * 16 + lm];
            frag_cd acc = {bias, bias, bias, bias};
            acc = __builtin_amdgcn_mfma_f32_16x16x32_bf16(a, bf, acc, 0, 0, 0);
#pragma unroll
            for (int r = 0; r < 4; r++) {
                const float tv = fast_tanh(acc[r]);
                t1[nt * 4 + r] = tv;
                sm[O_H1 + (mrow + quad * 4 + r) * LW2 + nt * 16 + lm] = (short)f2bs(tv);
            }
        }
    }

    // ---- fwd2: t2 = tanh(h1 @ W2 + b2); eij; gz2 = fc*W3*(1-t2^2) ----
    float fcr[4];
#pragma unroll
    for (int r = 0; r < 4; r++) fcr[r] = sFc[mrow + quad * 4 + r];
    {
        const frag_ab a0 = *(const frag_ab*)&sm[O_H1 + (mrow + lm) * LW2 + quad * 8];
        const frag_ab a1 = *(const frag_ab*)&sm[O_H1 + (mrow + lm) * LW2 + 32 + quad * 8];
        float er[4] = {0.0f, 0.0f, 0.0f, 0.0f};
#pragma unroll
        for (int nt = 0; nt < 4; nt++) {
            const int n = nt * 16 + lm;
            const frag_ab b0 = *(const frag_ab*)&sm[O_W2T + n * LW2 + quad * 8];
            const frag_ab b1f = *(const frag_ab*)&sm[O_W2T + n * LW2 + 32 + quad * 8];
            const float bias = sB2[n];
            frag_cd acc = {bias, bias, bias, bias};
            acc = __builtin_amdgcn_mfma_f32_16x16x32_bf16(a0, b0, acc, 0, 0, 0);
            acc = __builtin_amdgcn_mfma_f32_16x16x32_bf16(a1, b1f, acc, 0, 0, 0);
            const float w3n = sW3[n];
#pragma unroll
            for (int r = 0; r < 4; r++) {
                const float tv = fast_tanh(acc[r]);
                er[r] = fmaf(tv, w3n, er[r]);
                sm[O_GZ2 + (mrow + quad * 4 + r) * LW2 + n] =
                    (short)f2bs(fcr[r] * w3n * (1.0f - tv * tv));
            }
        }
#pragma unroll
        for (int off = 1; off < 16; off <<= 1) {
#pragma unroll
            for (int r = 0; r < 4; r++) er[r] += __shfl_xor(er[r], off, 64);
        }
        if (lm == 0) {
            const float b3v = b3[0];
#pragma unroll
            for (int r = 0; r < 4; r++)
                g_gdesc[(base + mrow + quad * 4 + r) * 20 + 17] = er[r] + b3v;
        }
    }

    // ---- bwd1: gz1 = (gz2 @ W2^T) * (1-h1^2) -> overwrite O_H1 ----
    {
        const frag_ab a0 = *(const frag_ab*)&sm[O_GZ2 + (mrow + lm) * LW2 + quad * 8];
        const frag_ab a1 = *(const frag_ab*)&sm[O_GZ2 + (mrow + lm) * LW2 + 32 + quad * 8];
#pragma unroll
        for (int nt = 0; nt < 4; nt++) {
            const int n = nt * 16 + lm;
            const frag_ab b0 = *(const frag_ab*)&sm[O_W2R + n * LW2 + quad * 8];
            const frag_ab b1f = *(const frag_ab*)&sm[O_W2R + n * LW2 + 32 + quad * 8];
            frag_cd acc = {0.0f, 0.0f, 0.0f, 0.0f};
            acc = __builtin_amdgcn_mfma_f32_16x16x32_bf16(a0, b0, acc, 0, 0, 0);
            acc = __builtin_amdgcn_mfma_f32_16x16x32_bf16(a1, b1f, acc, 0, 0, 0);
#pragma unroll
            for (int r = 0; r < 4; r++) {
                const float g = acc[r] * (1.0f - t1[nt * 4 + r] * t1[nt * 4 + r]);
                sm[O_H1 + (mrow + quad * 4 + r) * LW2 + n] = (short)f2bs(g);
            }
        }
    }

    // ---- bwd2: gdesc = gz1 @ W1^T ----
    {
        const frag_ab a0 = *(const frag_ab*)&sm[O_H1 + (mrow + lm) * LW2 + quad * 8];
        const frag_ab a1 = *(const frag_ab*)&sm[O_H1 + (mrow + lm) * LW2 + 32 + quad * 8];
#pragma unroll
        for (int nt = 0; nt < 2; nt++) {
            const int n = nt * 16 + lm;
            const frag_ab b0 = *(const frag_ab*)&sm[O_W1R + n * LW2 + quad * 8];
            const frag_ab b1f = *(const frag_ab*)&sm[O_W1R + n * LW2 + 32 + quad * 8];
            frag_cd acc = {0.0f, 0.0f, 0.0f, 0.0f};
            acc = __builtin_amdgcn_mfma_f32_16x16x32_bf16(a0, b0, acc, 0, 0, 0);
            acc = __builtin_amdgcn_mfma_f32_16x16x32_bf16(a1, b1f, acc, 0, 0, 0);
            if (n < ND) {
#pragma unroll
                for (int r = 0; r < 4; r++)
                    g_gdesc[(base + mrow + quad * 4 + r) * 20 + n] = acc[r];
            }
        }
    }
}

// ---------------- Kernel 3: per-atom backward -----------------------------
__global__ __launch_bounds__(256) void k_bwd_atom(const float* __restrict__ rij,
                                                  float* __restrict__ out) {
    __shared__ float su[K][3];
    __shared__ float sd_[K];
    __shared__ float sfcrik[K];
    __shared__ float sS[K][K + 1];
    __shared__ float sT[K][K + 1];
    __shared__ float sgG[K][NM];     // pre-multiplied by C_m
    __shared__ float sgu[K][3];
    __shared__ float sgf[K];
    const int atom = blockIdx.x, t = threadIdx.x, base = atom * K;

    if (t < K) {
        const float x = rij[3 * (base + t) + 0];
        const float y = rij[3 * (base + t) + 1];
        const float z = rij[3 * (base + t) + 2];
        const float d = sqrtf(x * x + y * y + z * z);
        const float inv = 1.0f / fmaxf(d, 1e-12f);
        su[t][0] = x * inv; su[t][1] = y * inv; su[t][2] = z * inv;
        sd_[t] = d;
        sfcrik[t] = 0.5f + 0.5f * __cosf(POC * d);
    }
    for (int idx = t; idx < K * NM; idx += 256) {
        const int k = idx / NM, m = idx - k * NM;
        sgG[k][m] = g_gdesc[(base + k) * 20 + NR + m] * __expf(CMC * (float)(m * m));
    }
    __syncthreads();

    for (int idx = t; idx < K * K; idx += 256) {
        const int k = idx / K, l = idx - k * K;
        const float c = su[k][0] * su[l][0] + su[k][1] * su[l][1] + su[k][2] * su[l][2];
        sS[k][l] = (k == l) ? 0.0f : c;
    }
    __syncthreads();

    for (int idx = t; idx < K * K; idx += 256) {
        const int k = idx / K, l = idx - k * K;
        const float cp1 = sS[k][l] + 1.0f;
        const float e0 = __expf(-4.0f * cp1 * cp1);
        const float e1 = __expf(E1C * cp1);
        float tm = e0;
        float T = sgG[k][0] * tm, U = 0.0f;
#pragma unroll
        for (int m = 1; m < NM; m++) {
            tm *= e1;
            const float q = sgG[k][m] * tm;
            T += q;
            U = fmaf((float)m, q, U);
        }
        const float Sp = cp1 * T - (2.0f / 11.0f) * U;
        sT[k][l] = T;
        sS[k][l] = (k == l) ? 0.0f : (-8.0f) * Sp;
    }
    __syncthreads();

    if (t < K) {
        float s = 0.0f;
#pragma unroll 4
        for (int kk = 0; kk < K; kk++) s += sT[kk][t];
        sgf[t] = s;
    } else if (t >= 64 && t < 64 + K) {
        const int k = t - 64;
        const float fk = sfcrik[k];
        float gx = 0.0f, gy = 0.0f, gz = 0.0f;
#pragma unroll 4
        for (int l = 0; l < K; l++) {
            const float w = fmaf(sS[k][l], sfcrik[l], sS[l][k] * fk);
            gx = fmaf(w, su[l][0], gx);
            gy = fmaf(w, su[l][1], gy);
            gz = fmaf(w, su[l][2], gz);
        }
        sgu[k][0] = gx; sgu[k][1] = gy; sgu[k][2] = gz;
    }
    __syncthreads();

    if (t < K) {
        const float d = sd_[t];
        const float ux = su[t][0], uy = su[t][1], uz = su[t][2];
        const float invd = 1.0f / d;
        float gfc = g_gdesc[(base + t) * 20 + 17];
        float gdR = 0.0f;
#pragma unroll
        for (int n = 0; n < NR; n++) {
            const float bn = (float)(n + 1) * POC;
            float sn, cn;
            __sincosf(bn * d, &sn, &cn);
            const float g = g_gdesc[(base + t) * 20 + n];
            gfc = fmaf(g, SQ * sn * invd, gfc);
            gdR = fmaf(g, SQ * (bn * cn - sn * invd) * invd, gdR);
        }
        float fc, dfc;
        if (d > RMIN_F) {
            float sa, ca;
            __sincosf(AFC * (d - RMIN_F), &sa, &ca);
            fc = 0.5f + 0.5f * ca;
            dfc = -0.5f * AFC * sa;
        } else { fc = 1.0f; dfc = 0.0f; }
        const float dfcrik = -0.5f * POC * __sinf(POC * d);

        const float gd = fc * gdR + gfc * dfc + sgf[t] * dfcrik;
        const float gux = sgu[t][0], guy = sgu[t][1], guz = sgu[t][2];
        const float dot = gux * ux + guy * uy + guz * uz;

        out[3 * (base + t) + 0] = fmaf(gd, ux, (gux - dot * ux) * invd);
        out[3 * (base + t) + 1] = fmaf(gd, uy, (guy - dot * uy) * invd);
        out[3 * (base + t) + 2] = fmaf(gd, uz, (guz - dot * uz) * invd);
    }
}

extern "C" void kernel_launch(void* const* d_in, const int* in_sizes, int n_in,
                              void* d_out, int out_size, void* d_ws, size_t ws_size,
                              hipStream_t stream) {
    (void)in_sizes; (void)n_in; (void)out_size; (void)d_ws; (void)ws_size;
    const float* rij = (const float*)d_in[0];
    // d_in[1] = unique_i (unused: dense K neighbors per atom)
    const float* W1 = (const float*)d_in[2];
    const float* b1 = (const float*)d_in[3];
    const float* W2 = (const float*)d_in[4];
    const float* b2 = (const float*)d_in[5];
    const float* W3 = (const float*)d_in[6];
    const float* b3 = (const float*)d_in[7];
    float* out = (float*)d_out;

    k_prep<<<48, 256, 0, stream>>>(W1, W2);
    k_fwd_atom<<<NATOMS, 192, 0, stream>>>(rij);
    k_mlp<<<P / 64, 256, 0, stream>>>(rij, b1, b2, W3, b3);
    k_bwd_atom<<<NATOMS, 256, 0, stream>>>(rij, out);
}

// Round 8
// 105.181 us; speedup vs baseline: 26.7146x; 1.0628x over previous
//
#include <hip/hip_runtime.h>
#include <hip/hip_bf16.h>

#define NATOMS 2048
#define K 48
#define P (NATOMS * K)
#define NR 5
#define NM 12
#define ND 17
#define HID 64

#define PI_F 3.14159265358979f
#define CUT 3.0f
#define RMIN_F 3.5f
#define AFC (-6.28318530717959f)   /* pi/(CUT-RMIN) = pi/(-0.5) */
#define POC (PI_F / CUT)           /* pi/3 */
#define SQ 0.816496580927726f      /* sqrt(2/3) */
#define E1C 1.45454545454545f      /* 16/11 */
#define CMC (-0.132231404958678f)  /* -16/121 */

// Packed bf16 weight layouts (built once per launch by k_prep).
// These are read as MFMA B-fragments directly from global (L2-broadcast).
__device__ unsigned short g_w1t[64 * 32];  // [n=h][k=j]  (k>=17 zero)
__device__ unsigned short g_w2t[64 * 64];  // [n=h2][k=h1]
__device__ unsigned short g_w2r[64 * 64];  // [n=h1][k=h2]
__device__ unsigned short g_w1r[32 * 64];  // [n=j][k=h]  (n>=17 zero)

using frag_ab = __attribute__((ext_vector_type(8))) short;
using frag_cd = __attribute__((ext_vector_type(4))) float;

__device__ __forceinline__ float fast_tanh(float x) {
    float cx = fminf(fmaxf(x, -15.0f), 15.0f);
    float t = __expf(2.0f * cx);
    return (t - 1.0f) / (t + 1.0f);
}

__device__ __forceinline__ unsigned short f2bs(float x) {
    __hip_bfloat16 b = __float2bfloat16(x);
    return __builtin_bit_cast(unsigned short, b);
}

// ---------------- Kernel 0: pack weights into MFMA-ready bf16 layouts -----
__global__ __launch_bounds__(256) void k_prep(const float* __restrict__ W1,
                                              const float* __restrict__ W2) {
    const int i = blockIdx.x * 256 + threadIdx.x;  // grid covers 12288
    if (i < 2048) {                                   // W1T[n][k]
        const int n = i >> 5, k = i & 31;
        g_w1t[i] = (k < ND) ? f2bs(W1[k * HID + n]) : (unsigned short)0;
    } else if (i < 2048 + 4096) {                     // W2T[n][k]
        const int j = i - 2048, n = j >> 6, k = j & 63;
        g_w2t[j] = f2bs(W2[k * HID + n]);
    } else if (i < 2048 + 8192) {                     // W2R[n][k]
        const int j = i - (2048 + 4096);
        g_w2r[j] = f2bs(W2[j]);
    } else if (i < 2048 + 8192 + 2048) {              // W1R[n][k]
        const int j = i - (2048 + 8192), n = j >> 6;
        g_w1r[j] = (n < ND) ? f2bs(W1[j]) : (unsigned short)0;
    }
}

// ---------------- Fused kernel: block = 1 atom (48 pairs), 4 waves --------
// LDS pool with barrier-protected aliases:
//   sc    (cosang, later S in-place)        9408 B   persistent
//   POOL  h1 (6912) | gz2 (6912) | desc (3840) = 17664 B
//     aliases: spart (9984, phases 2-3) over h1+gz2-start
//              sgG   (2304, phase 8)   over h1
//              sT    (9216, phase 8)   over gz2+desc
//   sgd   (gdesc+eij, [48][20] f32)         3840 B
//   smalls (srij/su/sfc/sfk/sd/se/sgf/sgu)  3264 B
#define SC_OFF    0
#define H1_OFF    9408
#define GZ2_OFF   16320
#define DESC_OFF  23232
#define SPART_OFF 9408
#define SGG_OFF   9408
#define ST_OFF    16320
#define SGD_OFF   27072
#define SRIJ_OFF  30912
#define SU_OFF    31488
#define SFC_OFF   32064
#define SFK_OFF   32256
#define SD_OFF    32448
#define SE_OFF    32640
#define SGF_OFF   33408
#define SGU_OFF   33600
#define SM_BYTES  34176

__global__ __launch_bounds__(256, 4) void k_fused(const float* __restrict__ rij,
                                                  const float* __restrict__ b1,
                                                  const float* __restrict__ b2,
                                                  const float* __restrict__ W3,
                                                  const float* __restrict__ b3,
                                                  float* __restrict__ out) {
    __shared__ __align__(16) char smem[SM_BYTES];
    float* sc    = (float*)(smem + SC_OFF);     // [k*49+l]
    short* h1S   = (short*)(smem + H1_OFF);     // [row*72+n]
    short* gz2S  = (short*)(smem + GZ2_OFF);    // [row*72+n]
    short* descS = (short*)(smem + DESC_OFF);   // [row*40+j]
    float* spart = (float*)(smem + SPART_OFF);  // [(ch*48+k)*13+m]
    float* sgG   = (float*)(smem + SGG_OFF);    // [k*12+m]
    float* sT    = (float*)(smem + ST_OFF);     // [k*48+l]
    float* sgd   = (float*)(smem + SGD_OFF);    // [k*20+{0..16:gdesc,17:eij}]
    float* srij  = (float*)(smem + SRIJ_OFF);
    float* su    = (float*)(smem + SU_OFF);     // [3k+c]
    float* sfc   = (float*)(smem + SFC_OFF);
    float* sfk   = (float*)(smem + SFK_OFF);
    float* sd    = (float*)(smem + SD_OFF);
    float* se    = (float*)(smem + SE_OFF);     // [w*48+row]
    float* sgf   = (float*)(smem + SGF_OFF);
    float* sgu   = (float*)(smem + SGU_OFF);    // [3k+c]

    const int t = threadIdx.x;
    const int base3 = blockIdx.x * (K * 3);

    // ---- phase 0: load rij coalesced; per-pair geometry + rbf ----
    if (t < K * 3) srij[t] = rij[base3 + t];
    __syncthreads();

    if (t < K) {
        const float x = srij[3 * t], y = srij[3 * t + 1], z = srij[3 * t + 2];
        const float d = sqrtf(x * x + y * y + z * z);
        const float inv = 1.0f / fmaxf(d, 1e-12f);
        su[3 * t] = x * inv; su[3 * t + 1] = y * inv; su[3 * t + 2] = z * inv;
        sd[t] = d;
        sfk[t] = 0.5f + 0.5f * __cosf(POC * d);
        const float fc = (d > RMIN_F) ? (0.5f + 0.5f * __cosf(AFC * (d - RMIN_F))) : 1.0f;
        sfc[t] = fc;
        const float s = SQ * fc / d;
#pragma unroll
        for (int n = 0; n < NR; n++) {
            const float bn = (float)(n + 1) * POC;
            descS[t * 40 + n] = (short)f2bs(s * __sinf(bn * d));
        }
#pragma unroll
        for (int c = ND; c < 32; c++) descS[t * 40 + c] = 0;
    }
    __syncthreads();

    // ---- phase 1: cosang ----
    for (int idx = t; idx < K * K; idx += 256) {
        const int k = idx / K, l = idx - k * K;
        const float c = su[3 * k] * su[3 * l] + su[3 * k + 1] * su[3 * l + 1]
                      + su[3 * k + 2] * su[3 * l + 2];
        sc[k * 49 + l] = (k == l) ? 0.0f : c;
    }
    __syncthreads();

    // ---- phase 2: 3-body partials (factorized Gaussian) ----
    if (t < 192) {
        const int ch = t / 48, k = t - ch * 48;
        float part[NM];
#pragma unroll
        for (int m = 0; m < NM; m++) part[m] = 0.0f;
#pragma unroll
        for (int li = 0; li < 12; li++) {
            const int l = ch * 12 + li;
            const float cp1 = sc[k * 49 + l] + 1.0f;
            const float e0 = __expf(-4.0f * cp1 * cp1) * sfk[l];
            const float e1 = __expf(E1C * cp1);
            float tm = e0;
            part[0] += tm;
#pragma unroll
            for (int m = 1; m < NM; m++) { tm *= e1; part[m] += tm; }
        }
#pragma unroll
        for (int m = 0; m < NM; m++) spart[(ch * 48 + k) * 13 + m] = part[m];
    }
    __syncthreads();

    // ---- phase 3: reduce partials -> desc cols 5..16 ----
    for (int idx = t; idx < K * NM; idx += 256) {
        const int k = idx / NM, m = idx - k * NM;
        const float cm = __expf(CMC * (float)(m * m));
        const float s = spart[(0 * 48 + k) * 13 + m] + spart[(1 * 48 + k) * 13 + m]
                      + spart[(2 * 48 + k) * 13 + m] + spart[(3 * 48 + k) * 13 + m];
        descS[k * 40 + NR + m] = (short)f2bs(s * cm);
    }
    __syncthreads();

    const int w = t >> 6, lane = t & 63, quad = lane >> 4, lm = lane & 15;
    const int n0 = w * 16 + lm;

    // ---- phase 4 (fwd1): h1 = tanh(desc @ W1 + b1); t1 kept in registers --
    float t1[3][4];
    {
        const frag_ab bf = *(const frag_ab*)&g_w1t[n0 * 32 + quad * 8];
        const float bias = b1[n0];
#pragma unroll
        for (int mt = 0; mt < 3; mt++) {
            const frag_ab a = *(const frag_ab*)&descS[(mt * 16 + lm) * 40 + quad * 8];
            frag_cd acc = {bias, bias, bias, bias};
            acc = __builtin_amdgcn_mfma_f32_16x16x32_bf16(a, bf, acc, 0, 0, 0);
#pragma unroll
            for (int r = 0; r < 4; r++) {
                const float tv = fast_tanh(acc[r]);
                t1[mt][r] = tv;
                h1S[(mt * 16 + quad * 4 + r) * 72 + n0] = (short)f2bs(tv);
            }
        }
    }
    __syncthreads();

    // ---- phase 5 (fwd2): t2 = tanh(h1@W2+b2); e partials; gz2 ----
    {
        const frag_ab b0 = *(const frag_ab*)&g_w2t[n0 * 64 + quad * 8];
        const frag_ab b1f = *(const frag_ab*)&g_w2t[n0 * 64 + 32 + quad * 8];
        const float bias = b2[n0];
        const float w3n = W3[n0];
#pragma unroll
        for (int mt = 0; mt < 3; mt++) {
            const frag_ab a0 = *(const frag_ab*)&h1S[(mt * 16 + lm) * 72 + quad * 8];
            const frag_ab a1 = *(const frag_ab*)&h1S[(mt * 16 + lm) * 72 + 32 + quad * 8];
            frag_cd acc = {bias, bias, bias, bias};
            acc = __builtin_amdgcn_mfma_f32_16x16x32_bf16(a0, b0, acc, 0, 0, 0);
            acc = __builtin_amdgcn_mfma_f32_16x16x32_bf16(a1, b1f, acc, 0, 0, 0);
            float ep[4];
#pragma unroll
            for (int r = 0; r < 4; r++) {
                const int row = mt * 16 + quad * 4 + r;
                const float tv = fast_tanh(acc[r]);
                ep[r] = tv * w3n;
                gz2S[row * 72 + n0] = (short)f2bs(sfc[row] * w3n * (1.0f - tv * tv));
            }
#pragma unroll
            for (int off = 1; off < 16; off <<= 1) {
#pragma unroll
                for (int r = 0; r < 4; r++) ep[r] += __shfl_xor(ep[r], off, 64);
            }
            if (lm == 0) {
#pragma unroll
                for (int r = 0; r < 4; r++) se[w * 48 + mt * 16 + quad * 4 + r] = ep[r];
            }
        }
    }
    __syncthreads();

    // ---- phase 6 (bwd1): gz1 = (gz2 @ W2^T)*(1-t1^2) -> overwrite h1S ----
    {
        const frag_ab b0 = *(const frag_ab*)&g_w2r[n0 * 64 + quad * 8];
        const frag_ab b1f = *(const frag_ab*)&g_w2r[n0 * 64 + 32 + quad * 8];
#pragma unroll
        for (int mt = 0; mt < 3; mt++) {
            const frag_ab a0 = *(const frag_ab*)&gz2S[(mt * 16 + lm) * 72 + quad * 8];
            const frag_ab a1 = *(const frag_ab*)&gz2S[(mt * 16 + lm) * 72 + 32 + quad * 8];
            frag_cd acc = {0.0f, 0.0f, 0.0f, 0.0f};
            acc = __builtin_amdgcn_mfma_f32_16x16x32_bf16(a0, b0, acc, 0, 0, 0);
            acc = __builtin_amdgcn_mfma_f32_16x16x32_bf16(a1, b1f, acc, 0, 0, 0);
#pragma unroll
            for (int r = 0; r < 4; r++) {
                const float g = acc[r] * (1.0f - t1[mt][r] * t1[mt][r]);
                h1S[(mt * 16 + quad * 4 + r) * 72 + n0] = (short)f2bs(g);
            }
        }
    }
    __syncthreads();

    // ---- phase 7 (bwd2): gdesc = gz1 @ W1^T -> sgd; eij from se ----
    for (int tid = w; tid < 6; tid += 4) {
        const int mt = tid >> 1, nt = tid & 1, n = nt * 16 + lm;
        const frag_ab b0 = *(const frag_ab*)&g_w1r[n * 64 + quad * 8];
        const frag_ab b1f = *(const frag_ab*)&g_w1r[n * 64 + 32 + quad * 8];
        const frag_ab a0 = *(const frag_ab*)&h1S[(mt * 16 + lm) * 72 + quad * 8];
        const frag_ab a1 = *(const frag_ab*)&h1S[(mt * 16 + lm) * 72 + 32 + quad * 8];
        frag_cd acc = {0.0f, 0.0f, 0.0f, 0.0f};
        acc = __builtin_amdgcn_mfma_f32_16x16x32_bf16(a0, b0, acc, 0, 0, 0);
        acc = __builtin_amdgcn_mfma_f32_16x16x32_bf16(a1, b1f, acc, 0, 0, 0);
        if (n < ND) {
#pragma unroll
            for (int r = 0; r < 4; r++)
                sgd[(mt * 16 + quad * 4 + r) * 20 + n] = acc[r];
        }
    }
    if (t < K)
        sgd[t * 20 + 17] = se[t] + se[48 + t] + se[96 + t] + se[144 + t] + b3[0];
    __syncthreads();

    // ---- phase 8a: sgG (gdesc_3b premultiplied by C_m) ----
    for (int idx = t; idx < K * NM; idx += 256) {
        const int k = idx / NM, m = idx - k * NM;
        sgG[idx] = sgd[k * 20 + NR + m] * __expf(CMC * (float)(m * m));
    }
    __syncthreads();

    // ---- phase 8b: S (in-place over sc) and T ----
    for (int idx = t; idx < K * K; idx += 256) {
        const int k = idx / K, l = idx - k * K;
        const float cp1 = sc[k * 49 + l] + 1.0f;
        const float e0 = __expf(-4.0f * cp1 * cp1);
        const float e1 = __expf(E1C * cp1);
        float tm = e0;
        float T = sgG[k * 12] * tm, U = 0.0f;
#pragma unroll
        for (int m = 1; m < NM; m++) {
            tm *= e1;
            const float q = sgG[k * 12 + m] * tm;
            T += q;
            U = fmaf((float)m, q, U);
        }
        const float Sp = cp1 * T - (2.0f / 11.0f) * U;
        sT[k * 48 + l] = T;
        sc[k * 49 + l] = (k == l) ? 0.0f : (-8.0f) * Sp;
    }
    __syncthreads();

    // ---- phase 8c: reductions ----
    if (t < K) {
        float s = 0.0f;
#pragma unroll 4
        for (int kk = 0; kk < K; kk++) s += sT[kk * 48 + t];
        sgf[t] = s;
    } else if (t >= 64 && t < 64 + K) {
        const int k = t - 64;
        const float fk = sfk[k];
        float gx = 0.0f, gy = 0.0f, gz = 0.0f;
#pragma unroll 4
        for (int l = 0; l < K; l++) {
            const float wgt = fmaf(sc[k * 49 + l], sfk[l], sc[l * 49 + k] * fk);
            gx = fmaf(wgt, su[3 * l], gx);
            gy = fmaf(wgt, su[3 * l + 1], gy);
            gz = fmaf(wgt, su[3 * l + 2], gz);
        }
        sgu[3 * k] = gx; sgu[3 * k + 1] = gy; sgu[3 * k + 2] = gz;
    }
    __syncthreads();

    // ---- phase 8d: assemble gradient, write out ----
    if (t < K) {
        const float d = sd[t];
        const float ux = su[3 * t], uy = su[3 * t + 1], uz = su[3 * t + 2];
        const float invd = 1.0f / d;
        float gfc = sgd[t * 20 + 17];
        float gdR = 0.0f;
#pragma unroll
        for (int n = 0; n < NR; n++) {
            const float bn = (float)(n + 1) * POC;
            float sn, cn;
            __sincosf(bn * d, &sn, &cn);
            const float g = sgd[t * 20 + n];
            gfc = fmaf(g, SQ * sn * invd, gfc);
            gdR = fmaf(g, SQ * (bn * cn - sn * invd) * invd, gdR);
        }
        const float fc = sfc[t];
        float dfc = 0.0f;
        if (d > RMIN_F) dfc = -0.5f * AFC * __sinf(AFC * (d - RMIN_F));
        const float dfcrik = -0.5f * POC * __sinf(POC * d);

        const float gd = fc * gdR + gfc * dfc + sgf[t] * dfcrik;
        const float gux = sgu[3 * t], guy = sgu[3 * t + 1], guz = sgu[3 * t + 2];
        const float dot = gux * ux + guy * uy + guz * uz;

        out[base3 + 3 * t + 0] = fmaf(gd, ux, (gux - dot * ux) * invd);
        out[base3 + 3 * t + 1] = fmaf(gd, uy, (guy - dot * uy) * invd);
        out[base3 + 3 * t + 2] = fmaf(gd, uz, (guz - dot * uz) * invd);
    }
}

extern "C" void kernel_launch(void* const* d_in, const int* in_sizes, int n_in,
                              void* d_out, int out_size, void* d_ws, size_t ws_size,
                              hipStream_t stream) {
    (void)in_sizes; (void)n_in; (void)out_size; (void)d_ws; (void)ws_size;
    const float* rij = (const float*)d_in[0];
    // d_in[1] = unique_i (unused: dense K neighbors per atom)
    const float* W1 = (const float*)d_in[2];
    const float* b1 = (const float*)d_in[3];
    const float* W2 = (const float*)d_in[4];
    const float* b2 = (const float*)d_in[5];
    const float* W3 = (const float*)d_in[6];
    const float* b3 = (const float*)d_in[7];
    float* out = (float*)d_out;

    k_prep<<<48, 256, 0, stream>>>(W1, W2);
    k_fused<<<NATOMS, 256, 0, stream>>>(rij, b1, b2, W3, b3, out);
}

// Round 9
// 102.355 us; speedup vs baseline: 27.4523x; 1.0276x over previous
//
#include <hip/hip_runtime.h>
#include <hip/hip_bf16.h>

#define NATOMS 2048
#define K 48
#define P (NATOMS * K)
#define NR 5
#define NM 12
#define ND 17
#define HID 64

#define PI_F 3.14159265358979f
#define CUT 3.0f
#define RMIN_F 3.5f
#define AFC (-6.28318530717959f)   /* pi/(CUT-RMIN) = pi/(-0.5) */
#define POC (PI_F / CUT)           /* pi/3 */
#define SQ 0.816496580927726f      /* sqrt(2/3) */
#define E1C 1.45454545454545f      /* 16/11 */
#define CMC (-0.132231404958678f)  /* -16/121 */

// Packed bf16 weight layouts (built once per launch by k_prep).
// Read as MFMA B-fragments directly from global (L2-broadcast).
__device__ unsigned short g_w1t[64 * 32];  // [n=h][k=j]  (k>=17 zero)
__device__ unsigned short g_w2t[64 * 64];  // [n=h2][k=h1]
__device__ unsigned short g_w2r[64 * 64];  // [n=h1][k=h2]
__device__ unsigned short g_w1r[32 * 64];  // [n=j][k=h]  (n>=17 zero)

using frag_ab = __attribute__((ext_vector_type(8))) short;
using frag_cd = __attribute__((ext_vector_type(4))) float;

__device__ __forceinline__ float fast_tanh(float x) {
    float cx = fminf(fmaxf(x, -15.0f), 15.0f);
    float t = __expf(2.0f * cx);
    return (t - 1.0f) / (t + 1.0f);
}

__device__ __forceinline__ unsigned short f2bs(float x) {
    __hip_bfloat16 b = __float2bfloat16(x);
    return __builtin_bit_cast(unsigned short, b);
}

// ---------------- Kernel 0: pack weights into MFMA-ready bf16 layouts -----
__global__ __launch_bounds__(256) void k_prep(const float* __restrict__ W1,
                                              const float* __restrict__ W2) {
    const int i = blockIdx.x * 256 + threadIdx.x;  // grid covers 12288
    if (i < 2048) {                                   // W1T[n][k]
        const int n = i >> 5, k = i & 31;
        g_w1t[i] = (k < ND) ? f2bs(W1[k * HID + n]) : (unsigned short)0;
    } else if (i < 2048 + 4096) {                     // W2T[n][k]
        const int j = i - 2048, n = j >> 6, k = j & 63;
        g_w2t[j] = f2bs(W2[k * HID + n]);
    } else if (i < 2048 + 8192) {                     // W2R[n][k]
        const int j = i - (2048 + 4096);
        g_w2r[j] = f2bs(W2[j]);
    } else if (i < 2048 + 8192 + 2048) {              // W1R[n][k]
        const int j = i - (2048 + 8192), n = j >> 6;
        g_w1r[j] = (n < ND) ? f2bs(W1[j]) : (unsigned short)0;
    }
}

// ---------------- Fused kernel: block = 1 atom (48 pairs), 4 waves --------
// LDS kept under 32 KB -> 5 blocks/CU (was 34.3 KB -> 4). Aliases (temporal):
//   spart (ph2-3) over h1+gz2 | se (ph5-7) over desc | sgG/sgu/sgf (ph8) over
//   h1 | sT (ph8) over gz2+desc-head. sc persistent (S written in place 8b).
#define SC_OFF    0        // 48*49*4 = 9408
#define H1_OFF    9408     // 48*72*2 = 6912
#define GZ2_OFF   16320    // 48*72*2 = 6912
#define DESC_OFF  23232    // 48*40*2 = 3840
#define SGD_OFF   27072    // 48*19*4 = 3648
#define SU_OFF    30720    // 576
#define SFC_OFF   31296    // 192
#define SFK_OFF   31488    // 192
#define SD_OFF    31680    // 192
#define SM_BYTES  31872
#define SPART_OFF 9408     // 4*48*13*4 = 9984 (<= h1+gz2 13824)
#define SGG_OFF   9408     // 48*12*4 = 2304
#define SGU_OFF   11712    // 576
#define SGF_OFF   12288    // 192
#define ST_OFF    16320    // 48*48*4 = 9216 (gz2 + 2304 of desc head)
#define SE_OFF    23232    // 768 (desc head; dead before sT write in 8b)

__global__ __launch_bounds__(256, 5) void k_fused(const float* __restrict__ rij,
                                                  const float* __restrict__ b1,
                                                  const float* __restrict__ b2,
                                                  const float* __restrict__ W3,
                                                  const float* __restrict__ b3,
                                                  float* __restrict__ out) {
    __shared__ __align__(16) char smem[SM_BYTES];
    float* sc    = (float*)(smem + SC_OFF);     // [k*49+l]
    short* h1S   = (short*)(smem + H1_OFF);     // [row*72+n]
    short* gz2S  = (short*)(smem + GZ2_OFF);    // [row*72+n]
    short* descS = (short*)(smem + DESC_OFF);   // [row*40+j]
    float* spart = (float*)(smem + SPART_OFF);  // [(ch*48+k)*13+m]
    float* sgG   = (float*)(smem + SGG_OFF);    // [k*12+m]
    float* sT    = (float*)(smem + ST_OFF);     // [k*48+l]
    float* sgd   = (float*)(smem + SGD_OFF);    // [k*19+{0..16:gdesc,17:eij}]
    float* su    = (float*)(smem + SU_OFF);     // [3k+c]
    float* sfc   = (float*)(smem + SFC_OFF);
    float* sfk   = (float*)(smem + SFK_OFF);
    float* sd    = (float*)(smem + SD_OFF);
    float* se    = (float*)(smem + SE_OFF);     // [w*48+row]
    float* sgf   = (float*)(smem + SGF_OFF);
    float* sgu   = (float*)(smem + SGU_OFF);    // [3k+c]

    const int t = threadIdx.x;
    const int base3 = blockIdx.x * (K * 3);

    // ---- phase 0: per-pair geometry + rbf (direct global loads) ----
    if (t < K) {
        const float x = rij[base3 + 3 * t];
        const float y = rij[base3 + 3 * t + 1];
        const float z = rij[base3 + 3 * t + 2];
        const float d = sqrtf(x * x + y * y + z * z);
        const float inv = 1.0f / fmaxf(d, 1e-12f);
        su[3 * t] = x * inv; su[3 * t + 1] = y * inv; su[3 * t + 2] = z * inv;
        sd[t] = d;
        sfk[t] = 0.5f + 0.5f * __cosf(POC * d);
        const float fc = (d > RMIN_F) ? (0.5f + 0.5f * __cosf(AFC * (d - RMIN_F))) : 1.0f;
        sfc[t] = fc;
        const float s = SQ * fc / d;
#pragma unroll
        for (int n = 0; n < NR; n++) {
            const float bn = (float)(n + 1) * POC;
            descS[t * 40 + n] = (short)f2bs(s * __sinf(bn * d));
        }
#pragma unroll
        for (int c = ND; c < 32; c++) descS[t * 40 + c] = 0;
    }
    __syncthreads();

    // ---- phase 1: cosang ----
    for (int idx = t; idx < K * K; idx += 256) {
        const int k = idx / K, l = idx - k * K;
        const float c = su[3 * k] * su[3 * l] + su[3 * k + 1] * su[3 * l + 1]
                      + su[3 * k + 2] * su[3 * l + 2];
        sc[k * 49 + l] = (k == l) ? 0.0f : c;
    }
    __syncthreads();

    // ---- phase 2: 3-body partials (factorized Gaussian) ----
    if (t < 192) {
        const int ch = t / 48, k = t - ch * 48;
        float part[NM];
#pragma unroll
        for (int m = 0; m < NM; m++) part[m] = 0.0f;
#pragma unroll
        for (int li = 0; li < 12; li++) {
            const int l = ch * 12 + li;
            const float cp1 = sc[k * 49 + l] + 1.0f;
            const float e0 = __expf(-4.0f * cp1 * cp1) * sfk[l];
            const float e1 = __expf(E1C * cp1);
            float tm = e0;
            part[0] += tm;
#pragma unroll
            for (int m = 1; m < NM; m++) { tm *= e1; part[m] += tm; }
        }
#pragma unroll
        for (int m = 0; m < NM; m++) spart[(ch * 48 + k) * 13 + m] = part[m];
    }
    __syncthreads();

    // ---- phase 3: reduce partials -> desc cols 5..16 ----
    for (int idx = t; idx < K * NM; idx += 256) {
        const int k = idx / NM, m = idx - k * NM;
        const float cm = __expf(CMC * (float)(m * m));
        const float s = spart[(0 * 48 + k) * 13 + m] + spart[(1 * 48 + k) * 13 + m]
                      + spart[(2 * 48 + k) * 13 + m] + spart[(3 * 48 + k) * 13 + m];
        descS[k * 40 + NR + m] = (short)f2bs(s * cm);
    }
    __syncthreads();

    const int w = t >> 6, lane = t & 63, quad = lane >> 4, lm = lane & 15;
    const int n0 = w * 16 + lm;

    // ---- phase 4 (fwd1): h1 = tanh(desc @ W1 + b1); t1 kept in registers --
    float t1[3][4];
    {
        const frag_ab bf = *(const frag_ab*)&g_w1t[n0 * 32 + quad * 8];
        const float bias = b1[n0];
#pragma unroll
        for (int mt = 0; mt < 3; mt++) {
            const frag_ab a = *(const frag_ab*)&descS[(mt * 16 + lm) * 40 + quad * 8];
            frag_cd acc = {bias, bias, bias, bias};
            acc = __builtin_amdgcn_mfma_f32_16x16x32_bf16(a, bf, acc, 0, 0, 0);
#pragma unroll
            for (int r = 0; r < 4; r++) {
                const float tv = fast_tanh(acc[r]);
                t1[mt][r] = tv;
                h1S[(mt * 16 + quad * 4 + r) * 72 + n0] = (short)f2bs(tv);
            }
        }
    }
    __syncthreads();

    // ---- phase 5 (fwd2): t2 = tanh(h1@W2+b2); e partials; gz2 ----
    {
        const frag_ab b0 = *(const frag_ab*)&g_w2t[n0 * 64 + quad * 8];
        const frag_ab b1f = *(const frag_ab*)&g_w2t[n0 * 64 + 32 + quad * 8];
        const float bias = b2[n0];
        const float w3n = W3[n0];
#pragma unroll
        for (int mt = 0; mt < 3; mt++) {
            const frag_ab a0 = *(const frag_ab*)&h1S[(mt * 16 + lm) * 72 + quad * 8];
            const frag_ab a1 = *(const frag_ab*)&h1S[(mt * 16 + lm) * 72 + 32 + quad * 8];
            frag_cd acc = {bias, bias, bias, bias};
            acc = __builtin_amdgcn_mfma_f32_16x16x32_bf16(a0, b0, acc, 0, 0, 0);
            acc = __builtin_amdgcn_mfma_f32_16x16x32_bf16(a1, b1f, acc, 0, 0, 0);
            float ep[4];
#pragma unroll
            for (int r = 0; r < 4; r++) {
                const int row = mt * 16 + quad * 4 + r;
                const float tv = fast_tanh(acc[r]);
                ep[r] = tv * w3n;
                gz2S[row * 72 + n0] = (short)f2bs(sfc[row] * w3n * (1.0f - tv * tv));
            }
#pragma unroll
            for (int off = 1; off < 16; off <<= 1) {
#pragma unroll
                for (int r = 0; r < 4; r++) ep[r] += __shfl_xor(ep[r], off, 64);
            }
            if (lm == 0) {
#pragma unroll
                for (int r = 0; r < 4; r++) se[w * 48 + mt * 16 + quad * 4 + r] = ep[r];
            }
        }
    }
    __syncthreads();

    // ---- phase 6 (bwd1): gz1 = (gz2 @ W2^T)*(1-t1^2) -> overwrite h1S ----
    {
        const frag_ab b0 = *(const frag_ab*)&g_w2r[n0 * 64 + quad * 8];
        const frag_ab b1f = *(const frag_ab*)&g_w2r[n0 * 64 + 32 + quad * 8];
#pragma unroll
        for (int mt = 0; mt < 3; mt++) {
            const frag_ab a0 = *(const frag_ab*)&gz2S[(mt * 16 + lm) * 72 + quad * 8];
            const frag_ab a1 = *(const frag_ab*)&gz2S[(mt * 16 + lm) * 72 + 32 + quad * 8];
            frag_cd acc = {0.0f, 0.0f, 0.0f, 0.0f};
            acc = __builtin_amdgcn_mfma_f32_16x16x32_bf16(a0, b0, acc, 0, 0, 0);
            acc = __builtin_amdgcn_mfma_f32_16x16x32_bf16(a1, b1f, acc, 0, 0, 0);
#pragma unroll
            for (int r = 0; r < 4; r++) {
                const float g = acc[r] * (1.0f - t1[mt][r] * t1[mt][r]);
                h1S[(mt * 16 + quad * 4 + r) * 72 + n0] = (short)f2bs(g);
            }
        }
    }
    __syncthreads();

    // ---- phase 7 (bwd2): gdesc = gz1 @ W1^T -> sgd; eij from se ----
    for (int tid = w; tid < 6; tid += 4) {
        const int mt = tid >> 1, nt = tid & 1, n = nt * 16 + lm;
        const frag_ab b0 = *(const frag_ab*)&g_w1r[n * 64 + quad * 8];
        const frag_ab b1f = *(const frag_ab*)&g_w1r[n * 64 + 32 + quad * 8];
        const frag_ab a0 = *(const frag_ab*)&h1S[(mt * 16 + lm) * 72 + quad * 8];
        const frag_ab a1 = *(const frag_ab*)&h1S[(mt * 16 + lm) * 72 + 32 + quad * 8];
        frag_cd acc = {0.0f, 0.0f, 0.0f, 0.0f};
        acc = __builtin_amdgcn_mfma_f32_16x16x32_bf16(a0, b0, acc, 0, 0, 0);
        acc = __builtin_amdgcn_mfma_f32_16x16x32_bf16(a1, b1f, acc, 0, 0, 0);
        if (n < ND) {
#pragma unroll
            for (int r = 0; r < 4; r++)
                sgd[(mt * 16 + quad * 4 + r) * 19 + n] = acc[r];
        }
    }
    if (t < K)
        sgd[t * 19 + 17] = se[t] + se[48 + t] + se[96 + t] + se[144 + t] + b3[0];
    __syncthreads();

    // ---- phase 8a: sgG (gdesc_3b premultiplied by C_m) ----
    for (int idx = t; idx < K * NM; idx += 256) {
        const int k = idx / NM, m = idx - k * NM;
        sgG[idx] = sgd[k * 19 + NR + m] * __expf(CMC * (float)(m * m));
    }
    __syncthreads();

    // ---- phase 8b: S (in-place over sc) and T ----
    for (int idx = t; idx < K * K; idx += 256) {
        const int k = idx / K, l = idx - k * K;
        const float cp1 = sc[k * 49 + l] + 1.0f;
        const float e0 = __expf(-4.0f * cp1 * cp1);
        const float e1 = __expf(E1C * cp1);
        float tm = e0;
        float T = sgG[k * 12] * tm, U = 0.0f;
#pragma unroll
        for (int m = 1; m < NM; m++) {
            tm *= e1;
            const float q = sgG[k * 12 + m] * tm;
            T += q;
            U = fmaf((float)m, q, U);
        }
        const float Sp = cp1 * T - (2.0f / 11.0f) * U;
        sT[k * 48 + l] = T;
        sc[k * 49 + l] = (k == l) ? 0.0f : (-8.0f) * Sp;
    }
    __syncthreads();

    // ---- phase 8c: reductions ----
    if (t < K) {
        float s = 0.0f;
#pragma unroll 4
        for (int kk = 0; kk < K; kk++) s += sT[kk * 48 + t];
        sgf[t] = s;
    } else if (t >= 64 && t < 64 + K) {
        const int k = t - 64;
        const float fk = sfk[k];
        float gx = 0.0f, gy = 0.0f, gz = 0.0f;
#pragma unroll 4
        for (int l = 0; l < K; l++) {
            const float wgt = fmaf(sc[k * 49 + l], sfk[l], sc[l * 49 + k] * fk);
            gx = fmaf(wgt, su[3 * l], gx);
            gy = fmaf(wgt, su[3 * l + 1], gy);
            gz = fmaf(wgt, su[3 * l + 2], gz);
        }
        sgu[3 * k] = gx; sgu[3 * k + 1] = gy; sgu[3 * k + 2] = gz;
    }
    __syncthreads();

    // ---- phase 8d: assemble gradient, write out ----
    if (t < K) {
        const float d = sd[t];
        const float ux = su[3 * t], uy = su[3 * t + 1], uz = su[3 * t + 2];
        const float invd = 1.0f / d;
        float gfc = sgd[t * 19 + 17];
        float gdR = 0.0f;
#pragma unroll
        for (int n = 0; n < NR; n++) {
            const float bn = (float)(n + 1) * POC;
            float sn, cn;
            __sincosf(bn * d, &sn, &cn);
            const float g = sgd[t * 19 + n];
            gfc = fmaf(g, SQ * sn * invd, gfc);
            gdR = fmaf(g, SQ * (bn * cn - sn * invd) * invd, gdR);
        }
        const float fc = sfc[t];
        float dfc = 0.0f;
        if (d > RMIN_F) dfc = -0.5f * AFC * __sinf(AFC * (d - RMIN_F));
        const float dfcrik = -0.5f * POC * __sinf(POC * d);

        const float gd = fc * gdR + gfc * dfc + sgf[t] * dfcrik;
        const float gux = sgu[3 * t], guy = sgu[3 * t + 1], guz = sgu[3 * t + 2];
        const float dot = gux * ux + guy * uy + guz * uz;

        out[base3 + 3 * t + 0] = fmaf(gd, ux, (gux - dot * ux) * invd);
        out[base3 + 3 * t + 1] = fmaf(gd, uy, (guy - dot * uy) * invd);
        out[base3 + 3 * t + 2] = fmaf(gd, uz, (guz - dot * uz) * invd);
    }
}

extern "C" void kernel_launch(void* const* d_in, const int* in_sizes, int n_in,
                              void* d_out, int out_size, void* d_ws, size_t ws_size,
                              hipStream_t stream) {
    (void)in_sizes; (void)n_in; (void)out_size; (void)d_ws; (void)ws_size;
    const float* rij = (const float*)d_in[0];
    // d_in[1] = unique_i (unused: dense K neighbors per atom)
    const float* W1 = (const float*)d_in[2];
    const float* b1 = (const float*)d_in[3];
    const float* W2 = (const float*)d_in[4];
    const float* b2 = (const float*)d_in[5];
    const float* W3 = (const float*)d_in[6];
    const float* b3 = (const float*)d_in[7];
    float* out = (float*)d_out;

    k_prep<<<48, 256, 0, stream>>>(W1, W2);
    k_fused<<<NATOMS, 256, 0, stream>>>(rij, b1, b2, W3, b3, out);
}

// Round 10
// 101.384 us; speedup vs baseline: 27.7152x; 1.0096x over previous
//
#include <hip/hip_runtime.h>
#include <hip/hip_bf16.h>

#define NATOMS 2048
#define K 48
#define P (NATOMS * K)
#define NR 5
#define NM 12
#define ND 17
#define HID 64

#define PI_F 3.14159265358979f
#define CUT 3.0f
#define RMIN_F 3.5f
#define AFC (-6.28318530717959f)   /* pi/(CUT-RMIN) = pi/(-0.5) */
#define POC (PI_F / CUT)           /* pi/3 */
#define SQ 0.816496580927726f      /* sqrt(2/3) */
#define E1C 1.45454545454545f      /* 16/11 */
#define CMC (-0.132231404958678f)  /* -16/121 */

// Packed bf16 weight layouts (built once per launch by k_prep).
// Read as MFMA B-fragments directly from global (L2-broadcast).
__device__ unsigned short g_w1t[64 * 32];  // [n=h][k=j]  (k>=17 zero)
__device__ unsigned short g_w2t[64 * 64];  // [n=h2][k=h1]
__device__ unsigned short g_w2r[64 * 64];  // [n=h1][k=h2]
__device__ unsigned short g_w1r[32 * 64];  // [n=j][k=h]  (n>=17 zero)

using frag_ab = __attribute__((ext_vector_type(8))) short;
using frag_cd = __attribute__((ext_vector_type(4))) float;

__device__ __forceinline__ float fast_tanh(float x) {
    float cx = fminf(fmaxf(x, -15.0f), 15.0f);
    float t = __expf(2.0f * cx);
    return (t - 1.0f) / (t + 1.0f);
}

__device__ __forceinline__ unsigned short f2bs(float x) {
    __hip_bfloat16 b = __float2bfloat16(x);
    return __builtin_bit_cast(unsigned short, b);
}

// ---------------- Kernel 0: pack weights into MFMA-ready bf16 layouts -----
__global__ __launch_bounds__(256) void k_prep(const float* __restrict__ W1,
                                              const float* __restrict__ W2) {
    const int i = blockIdx.x * 256 + threadIdx.x;  // grid covers 12288
    if (i < 2048) {                                   // W1T[n][k]
        const int n = i >> 5, k = i & 31;
        g_w1t[i] = (k < ND) ? f2bs(W1[k * HID + n]) : (unsigned short)0;
    } else if (i < 2048 + 4096) {                     // W2T[n][k]
        const int j = i - 2048, n = j >> 6, k = j & 63;
        g_w2t[j] = f2bs(W2[k * HID + n]);
    } else if (i < 2048 + 8192) {                     // W2R[n][k]
        const int j = i - (2048 + 4096);
        g_w2r[j] = f2bs(W2[j]);
    } else if (i < 2048 + 8192 + 2048) {              // W1R[n][k]
        const int j = i - (2048 + 8192), n = j >> 6;
        g_w1r[j] = (n < ND) ? f2bs(W1[j]) : (unsigned short)0;
    }
}

// ---------------- Fused kernel: block = 1 atom (48 pairs), 4 waves --------
// Temporal LDS aliases (all barrier-protected):
//   spart (ph2-3) over h1+gz2 | se (ph5-7) over desc head | sgG/mgG/sgu4
//   (ph8) over h1 | sT (ph8) over gz2+desc head | sgf4 (ph8) over desc tail.
#define SC_OFF    0        // 48*49*4 = 9408 (persistent; S in-place in 8b)
#define H1_OFF    9408     // 48*72*2 = 6912
#define GZ2_OFF   16320    // 48*72*2 = 6912
#define DESC_OFF  23232    // 48*40*2 = 3840
#define SGD_OFF   27072    // 48*19*4 = 3648
#define SU_OFF    30720    // 576
#define SFC_OFF   31296    // 192
#define SFK_OFF   31488    // 192
#define SD_OFF    31680    // 192
#define SCM_OFF   31872    // 48 (C_m table)
#define SM_BYTES  31920
#define SPART_OFF 9408     // 4*48*13*4 = 9984
#define SGG_OFF   9408     // 576*4 = 2304
#define MGG_OFF   11712    // 2304
#define SGU4_OFF  14016    // 4*48*3*4 = 2304 (ends 16320)
#define ST_OFF    16320    // 48*48*4 = 9216 (ends 25536)
#define SGF4_OFF  25536    // 4*48*4 = 768 (desc tail; desc dead after ph4)
#define SE_OFF    23232    // 768 (desc head; dead before sT write in 8b)

__global__ __launch_bounds__(256, 5) void k_fused(const float* __restrict__ rij,
                                                  const float* __restrict__ b1,
                                                  const float* __restrict__ b2,
                                                  const float* __restrict__ W3,
                                                  const float* __restrict__ b3,
                                                  float* __restrict__ out) {
    __shared__ __align__(16) char smem[SM_BYTES];
    float* sc    = (float*)(smem + SC_OFF);     // [k*49+l]
    short* h1S   = (short*)(smem + H1_OFF);     // [row*72+n]
    short* gz2S  = (short*)(smem + GZ2_OFF);    // [row*72+n]
    short* descS = (short*)(smem + DESC_OFF);   // [row*40+j]
    float* spart = (float*)(smem + SPART_OFF);  // [(ch*48+k)*13+m]
    float* sgG   = (float*)(smem + SGG_OFF);    // [k*12+m]
    float* mgG   = (float*)(smem + MGG_OFF);    // [k*12+m] = m*sgG
    float* sT    = (float*)(smem + ST_OFF);     // [k*48+l]
    float* sgd   = (float*)(smem + SGD_OFF);    // [k*19+{0..16:gdesc,17:eij}]
    float* su    = (float*)(smem + SU_OFF);     // [3k+c]
    float* sfc   = (float*)(smem + SFC_OFF);
    float* sfk   = (float*)(smem + SFK_OFF);
    float* sd    = (float*)(smem + SD_OFF);
    float* scm   = (float*)(smem + SCM_OFF);    // C_m, m=0..11
    float* se    = (float*)(smem + SE_OFF);     // [w*48+row]
    float* sgf4  = (float*)(smem + SGF4_OFF);   // [w*48+l]
    float* sgu4  = (float*)(smem + SGU4_OFF);   // [(w*48+k)*3+c]

    const int t = threadIdx.x;
    const int base3 = blockIdx.x * (K * 3);

    // ---- phase 0: per-pair geometry (no rbf here); C_m table ----
    if (t < K) {
        const float x = rij[base3 + 3 * t];
        const float y = rij[base3 + 3 * t + 1];
        const float z = rij[base3 + 3 * t + 2];
        const float d = sqrtf(x * x + y * y + z * z);
        const float inv = 1.0f / fmaxf(d, 1e-12f);
        su[3 * t] = x * inv; su[3 * t + 1] = y * inv; su[3 * t + 2] = z * inv;
        sd[t] = d;
        sfk[t] = 0.5f + 0.5f * __cosf(POC * d);
        sfc[t] = (d > RMIN_F) ? (0.5f + 0.5f * __cosf(AFC * (d - RMIN_F))) : 1.0f;
#pragma unroll
        for (int c = ND; c < 32; c++) descS[t * 40 + c] = 0;  // K-pad
    }
    if (t >= 64 && t < 64 + NM) {
        const int m = t - 64;
        scm[m] = __expf(CMC * (float)(m * m));
    }
    __syncthreads();

    // ---- phase 1: cosang ----
    for (int idx = t; idx < K * K; idx += 256) {
        const int k = idx / K, l = idx - k * K;
        const float c = su[3 * k] * su[3 * l] + su[3 * k + 1] * su[3 * l + 1]
                      + su[3 * k + 2] * su[3 * l + 2];
        sc[k * 49 + l] = (k == l) ? 0.0f : c;
    }
    __syncthreads();

    // ---- phase 2: waves 0-2: 3-body partials; wave 3: rbf ----
    if (t < 192) {
        const int ch = t / 48, k = t - ch * 48;
        float part[NM];
#pragma unroll
        for (int m = 0; m < NM; m++) part[m] = 0.0f;
#pragma unroll
        for (int li = 0; li < 12; li++) {
            const int l = ch * 12 + li;
            const float cp1 = sc[k * 49 + l] + 1.0f;
            const float e0 = __expf(-4.0f * cp1 * cp1) * sfk[l];
            const float e1 = __expf(E1C * cp1);
            float tm = e0;
            part[0] += tm;
#pragma unroll
            for (int m = 1; m < NM; m++) { tm *= e1; part[m] += tm; }
        }
#pragma unroll
        for (int m = 0; m < NM; m++) spart[(ch * 48 + k) * 13 + m] = part[m];
    } else {
#pragma unroll
        for (int r = 0; r < 4; r++) {
            const int idx = (t - 192) + 64 * r;     // 240 = 48 pairs x 5 rbf
            if (idx < K * NR) {
                const int p = idx / NR, n = idx - NR * p;
                const float d = sd[p];
                const float s = SQ * sfc[p] / d;
                descS[p * 40 + n] = (short)f2bs(s * __sinf((float)(n + 1) * POC * d));
            }
        }
    }
    __syncthreads();

    // ---- phase 3: reduce partials -> desc cols 5..16 ----
    for (int idx = t; idx < K * NM; idx += 256) {
        const int k = idx / NM, m = idx - k * NM;
        const float s = spart[(0 * 48 + k) * 13 + m] + spart[(1 * 48 + k) * 13 + m]
                      + spart[(2 * 48 + k) * 13 + m] + spart[(3 * 48 + k) * 13 + m];
        descS[k * 40 + NR + m] = (short)f2bs(s * scm[m]);
    }
    __syncthreads();

    const int w = t >> 6, lane = t & 63, quad = lane >> 4, lm = lane & 15;
    const int n0 = w * 16 + lm;

    // ---- phase 4 (fwd1): h1 = tanh(desc @ W1 + b1); t1 in registers ----
    float t1[3][4];
    {
        const frag_ab bf = *(const frag_ab*)&g_w1t[n0 * 32 + quad * 8];
        const float bias = b1[n0];
#pragma unroll
        for (int mt = 0; mt < 3; mt++) {
            const frag_ab a = *(const frag_ab*)&descS[(mt * 16 + lm) * 40 + quad * 8];
            frag_cd acc = {bias, bias, bias, bias};
            acc = __builtin_amdgcn_mfma_f32_16x16x32_bf16(a, bf, acc, 0, 0, 0);
#pragma unroll
            for (int r = 0; r < 4; r++) {
                const float tv = fast_tanh(acc[r]);
                t1[mt][r] = tv;
                h1S[(mt * 16 + quad * 4 + r) * 72 + n0] = (short)f2bs(tv);
            }
        }
    }
    __syncthreads();

    // ---- phase 5 (fwd2): t2 = tanh(h1@W2+b2); e partials; gz2 ----
    {
        const frag_ab b0 = *(const frag_ab*)&g_w2t[n0 * 64 + quad * 8];
        const frag_ab b1f = *(const frag_ab*)&g_w2t[n0 * 64 + 32 + quad * 8];
        const float bias = b2[n0];
        const float w3n = W3[n0];
#pragma unroll
        for (int mt = 0; mt < 3; mt++) {
            const frag_ab a0 = *(const frag_ab*)&h1S[(mt * 16 + lm) * 72 + quad * 8];
            const frag_ab a1 = *(const frag_ab*)&h1S[(mt * 16 + lm) * 72 + 32 + quad * 8];
            frag_cd acc = {bias, bias, bias, bias};
            acc = __builtin_amdgcn_mfma_f32_16x16x32_bf16(a0, b0, acc, 0, 0, 0);
            acc = __builtin_amdgcn_mfma_f32_16x16x32_bf16(a1, b1f, acc, 0, 0, 0);
            float ep[4];
#pragma unroll
            for (int r = 0; r < 4; r++) {
                const int row = mt * 16 + quad * 4 + r;
                const float tv = fast_tanh(acc[r]);
                ep[r] = tv * w3n;
                gz2S[row * 72 + n0] = (short)f2bs(sfc[row] * w3n * (1.0f - tv * tv));
            }
#pragma unroll
            for (int off = 1; off < 16; off <<= 1) {
#pragma unroll
                for (int r = 0; r < 4; r++) ep[r] += __shfl_xor(ep[r], off, 64);
            }
            if (lm == 0) {
#pragma unroll
                for (int r = 0; r < 4; r++) se[w * 48 + mt * 16 + quad * 4 + r] = ep[r];
            }
        }
    }
    __syncthreads();

    // ---- phase 6 (bwd1): gz1 = (gz2 @ W2^T)*(1-t1^2) -> overwrite h1S ----
    {
        const frag_ab b0 = *(const frag_ab*)&g_w2r[n0 * 64 + quad * 8];
        const frag_ab b1f = *(const frag_ab*)&g_w2r[n0 * 64 + 32 + quad * 8];
#pragma unroll
        for (int mt = 0; mt < 3; mt++) {
            const frag_ab a0 = *(const frag_ab*)&gz2S[(mt * 16 + lm) * 72 + quad * 8];
            const frag_ab a1 = *(const frag_ab*)&gz2S[(mt * 16 + lm) * 72 + 32 + quad * 8];
            frag_cd acc = {0.0f, 0.0f, 0.0f, 0.0f};
            acc = __builtin_amdgcn_mfma_f32_16x16x32_bf16(a0, b0, acc, 0, 0, 0);
            acc = __builtin_amdgcn_mfma_f32_16x16x32_bf16(a1, b1f, acc, 0, 0, 0);
#pragma unroll
            for (int r = 0; r < 4; r++) {
                const float g = acc[r] * (1.0f - t1[mt][r] * t1[mt][r]);
                h1S[(mt * 16 + quad * 4 + r) * 72 + n0] = (short)f2bs(g);
            }
        }
    }
    __syncthreads();

    // ---- phase 7 (bwd2): gdesc = gz1 @ W1^T -> sgd; eij from se ----
    for (int tid = w; tid < 6; tid += 4) {
        const int mt = tid >> 1, nt = tid & 1, n = nt * 16 + lm;
        const frag_ab b0 = *(const frag_ab*)&g_w1r[n * 64 + quad * 8];
        const frag_ab b1f = *(const frag_ab*)&g_w1r[n * 64 + 32 + quad * 8];
        const frag_ab a0 = *(const frag_ab*)&h1S[(mt * 16 + lm) * 72 + quad * 8];
        const frag_ab a1 = *(const frag_ab*)&h1S[(mt * 16 + lm) * 72 + 32 + quad * 8];
        frag_cd acc = {0.0f, 0.0f, 0.0f, 0.0f};
        acc = __builtin_amdgcn_mfma_f32_16x16x32_bf16(a0, b0, acc, 0, 0, 0);
        acc = __builtin_amdgcn_mfma_f32_16x16x32_bf16(a1, b1f, acc, 0, 0, 0);
        if (n < ND) {
#pragma unroll
            for (int r = 0; r < 4; r++)
                sgd[(mt * 16 + quad * 4 + r) * 19 + n] = acc[r];
        }
    }
    if (t < K)
        sgd[t * 19 + 17] = se[t] + se[48 + t] + se[96 + t] + se[144 + t] + b3[0];
    __syncthreads();

    // ---- phase 8a: sgG = gdesc_3b * C_m; mgG = m * sgG ----
    for (int idx = t; idx < K * NM; idx += 256) {
        const int k = idx / NM, m = idx - k * NM;
        const float g = sgd[k * 19 + NR + m] * scm[m];
        sgG[idx] = g;
        mgG[idx] = (float)m * g;
    }
    __syncthreads();

    // ---- phase 8b: fixed-k dual Horner: T = e0*P(x), U = e0*x*P'(x) ----
    if (t < 192) {
        const int ch = t / 48, k = t - ch * 48;
        float gg[NM], mg[NM];
#pragma unroll
        for (int m = 0; m < NM; m++) { gg[m] = sgG[k * 12 + m]; mg[m] = mgG[k * 12 + m]; }
#pragma unroll
        for (int li = 0; li < 12; li++) {
            const int l = ch * 12 + li;
            const float cp1 = sc[k * 49 + l] + 1.0f;
            const float e0 = __expf(-4.0f * cp1 * cp1);
            const float x = __expf(E1C * cp1);
            float Pv = gg[11], Dv = mg[11];
#pragma unroll
            for (int m = 10; m >= 1; m--) {
                Pv = fmaf(Pv, x, gg[m]);
                Dv = fmaf(Dv, x, mg[m]);
            }
            Pv = fmaf(Pv, x, gg[0]);
            const float T = e0 * Pv;
            const float U = e0 * x * Dv;
            const float Sp = fmaf(cp1, T, -(2.0f / 11.0f) * U);
            sT[k * 48 + l] = T;
            sc[k * 49 + l] = (k == l) ? 0.0f : (-8.0f) * Sp;
        }
    }
    __syncthreads();

    // ---- phase 8c: partial reductions, all 4 waves ----
    if (lane < K) {
        float s = 0.0f;
#pragma unroll
        for (int kk = 12 * w; kk < 12 * w + 12; kk++) s += sT[kk * 48 + lane];
        sgf4[w * 48 + lane] = s;

        const int k = lane;
        const float fk = sfk[k];
        float gx = 0.0f, gy = 0.0f, gz = 0.0f;
#pragma unroll
        for (int l = 12 * w; l < 12 * w + 12; l++) {
            const float wgt = fmaf(sc[k * 49 + l], sfk[l], sc[l * 49 + k] * fk);
            gx = fmaf(wgt, su[3 * l], gx);
            gy = fmaf(wgt, su[3 * l + 1], gy);
            gz = fmaf(wgt, su[3 * l + 2], gz);
        }
        sgu4[(w * 48 + k) * 3 + 0] = gx;
        sgu4[(w * 48 + k) * 3 + 1] = gy;
        sgu4[(w * 48 + k) * 3 + 2] = gz;
    }
    __syncthreads();

    // ---- phase 8d: combine partials, assemble gradient, write out ----
    if (t < K) {
        const float sgf_t = sgf4[t] + sgf4[48 + t] + sgf4[96 + t] + sgf4[144 + t];
        float gux = 0.0f, guy = 0.0f, guz = 0.0f;
#pragma unroll
        for (int ww = 0; ww < 4; ww++) {
            gux += sgu4[(ww * 48 + t) * 3 + 0];
            guy += sgu4[(ww * 48 + t) * 3 + 1];
            guz += sgu4[(ww * 48 + t) * 3 + 2];
        }
        const float d = sd[t];
        const float ux = su[3 * t], uy = su[3 * t + 1], uz = su[3 * t + 2];
        const float invd = 1.0f / d;
        float gfc = sgd[t * 19 + 17];
        float gdR = 0.0f;
#pragma unroll
        for (int n = 0; n < NR; n++) {
            const float bn = (float)(n + 1) * POC;
            float sn, cn;
            __sincosf(bn * d, &sn, &cn);
            const float g = sgd[t * 19 + n];
            gfc = fmaf(g, SQ * sn * invd, gfc);
            gdR = fmaf(g, SQ * (bn * cn - sn * invd) * invd, gdR);
        }
        const float fc = sfc[t];
        float dfc = 0.0f;
        if (d > RMIN_F) dfc = -0.5f * AFC * __sinf(AFC * (d - RMIN_F));
        const float dfcrik = -0.5f * POC * __sinf(POC * d);

        const float gd = fc * gdR + gfc * dfc + sgf_t * dfcrik;
        const float dot = gux * ux + guy * uy + guz * uz;

        out[base3 + 3 * t + 0] = fmaf(gd, ux, (gux - dot * ux) * invd);
        out[base3 + 3 * t + 1] = fmaf(gd, uy, (guy - dot * uy) * invd);
        out[base3 + 3 * t + 2] = fmaf(gd, uz, (guz - dot * uz) * invd);
    }
}

extern "C" void kernel_launch(void* const* d_in, const int* in_sizes, int n_in,
                              void* d_out, int out_size, void* d_ws, size_t ws_size,
                              hipStream_t stream) {
    (void)in_sizes; (void)n_in; (void)out_size; (void)d_ws; (void)ws_size;
    const float* rij = (const float*)d_in[0];
    // d_in[1] = unique_i (unused: dense K neighbors per atom)
    const float* W1 = (const float*)d_in[2];
    const float* b1 = (const float*)d_in[3];
    const float* W2 = (const float*)d_in[4];
    const float* b2 = (const float*)d_in[5];
    const float* W3 = (const float*)d_in[6];
    const float* b3 = (const float*)d_in[7];
    float* out = (float*)d_out;

    k_prep<<<48, 256, 0, stream>>>(W1, W2);
    k_fused<<<NATOMS, 256, 0, stream>>>(rij, b1, b2, W3, b3, out);
}

// Round 11
// 98.665 us; speedup vs baseline: 28.4788x; 1.0276x over previous
//
#include <hip/hip_runtime.h>
#include <hip/hip_bf16.h>

#define NATOMS 2048
#define K 48
#define P (NATOMS * K)
#define NR 5
#define NM 12
#define ND 17
#define HID 64

#define PI_F 3.14159265358979f
#define CUT 3.0f
#define RMIN_F 3.5f
#define AFC (-6.28318530717959f)   /* pi/(CUT-RMIN) = pi/(-0.5) */
#define POC (PI_F / CUT)           /* pi/3 */
#define SQ 0.816496580927726f      /* sqrt(2/3) */
#define E1C 1.45454545454545f      /* 16/11 */
#define CMC (-0.132231404958678f)  /* -16/121 */

// Packed bf16 weight layouts (built once per launch by k_prep).
// Read as MFMA B-fragments directly from global (L2-broadcast).
__device__ unsigned short g_w1t[64 * 32];  // [n=h][k=j]  (k>=17 zero)
__device__ unsigned short g_w2t[64 * 64];  // [n=h2][k=h1]
__device__ unsigned short g_w2r[64 * 64];  // [n=h1][k=h2]
__device__ unsigned short g_w1r[32 * 64];  // [n=j][k=h]  (n>=17 zero)

using frag_ab = __attribute__((ext_vector_type(8))) short;
using frag_cd = __attribute__((ext_vector_type(4))) float;

// 5-op tanh: 1 - 2/(e^2x + 1). No clamp needed: exp->inf -> rcp 0 -> 1;
// exp->0 -> -1. (was 8 ops with clamp; 24 tanh/thread in MLP phases)
__device__ __forceinline__ float fast_tanh(float x) {
    const float t = __expf(2.0f * x);
    return 1.0f - 2.0f / (t + 1.0f);
}

__device__ __forceinline__ unsigned short f2bs(float x) {
    __hip_bfloat16 b = __float2bfloat16(x);
    return __builtin_bit_cast(unsigned short, b);
}

// ---------------- Kernel 0: pack weights into MFMA-ready bf16 layouts -----
__global__ __launch_bounds__(256) void k_prep(const float* __restrict__ W1,
                                              const float* __restrict__ W2) {
    const int i = blockIdx.x * 256 + threadIdx.x;  // grid covers 12288
    if (i < 2048) {                                   // W1T[n][k]
        const int n = i >> 5, k = i & 31;
        g_w1t[i] = (k < ND) ? f2bs(W1[k * HID + n]) : (unsigned short)0;
    } else if (i < 2048 + 4096) {                     // W2T[n][k]
        const int j = i - 2048, n = j >> 6, k = j & 63;
        g_w2t[j] = f2bs(W2[k * HID + n]);
    } else if (i < 2048 + 8192) {                     // W2R[n][k]
        const int j = i - (2048 + 4096);
        g_w2r[j] = f2bs(W2[j]);
    } else if (i < 2048 + 8192 + 2048) {              // W1R[n][k]
        const int j = i - (2048 + 8192), n = j >> 6;
        g_w1r[j] = (n < ND) ? f2bs(W1[j]) : (unsigned short)0;
    }
}

// ---------------- Fused kernel: block = 1 atom (48 pairs), 4 waves --------
#define SC_OFF    0        // 48*49*4 = 9408 (persistent; S in-place in 8b)
#define H1_OFF    9408     // 48*72*2 = 6912
#define GZ2_OFF   16320    // 48*72*2 = 6912
#define DESC_OFF  23232    // 48*40*2 = 3840
#define SGD_OFF   27072    // 48*19*4 = 3648
#define SU_OFF    30720    // 576
#define SFC_OFF   31296    // 192
#define SFK_OFF   31488    // 192
#define SD_OFF    31680    // 192
#define SCM_OFF   31872    // 48 (C_m table)
#define SM_BYTES  31920
#define SPART_OFF 9408     // 4*48*13*4 = 9984
#define SGG_OFF   9408     // 2304
#define MGG_OFF   11712    // 2304
#define SGU4_OFF  14016    // 2304 (ends 16320)
#define ST_OFF    16320    // 9216 (ends 25536)
#define SGF4_OFF  25536    // 768 (desc tail; desc dead after ph4)
#define SE_OFF    23232    // 768 (desc head; dead before sT write in 8b)

__global__ __launch_bounds__(256, 5) void k_fused(const float* __restrict__ rij,
                                                  const float* __restrict__ b1,
                                                  const float* __restrict__ b2,
                                                  const float* __restrict__ W3,
                                                  const float* __restrict__ b3,
                                                  float* __restrict__ out) {
    __shared__ __align__(16) char smem[SM_BYTES];
    float* sc    = (float*)(smem + SC_OFF);     // [k*49+l]
    short* h1S   = (short*)(smem + H1_OFF);     // [row*72+n]
    short* gz2S  = (short*)(smem + GZ2_OFF);    // [row*72+n]
    short* descS = (short*)(smem + DESC_OFF);   // [row*40+j]
    float* spart = (float*)(smem + SPART_OFF);  // [(ch*48+k)*13+m]
    float* sgG   = (float*)(smem + SGG_OFF);    // [k*12+m]
    float* mgG   = (float*)(smem + MGG_OFF);    // [k*12+m] = m*sgG
    float* sT    = (float*)(smem + ST_OFF);     // [k*48+l]
    float* sgd   = (float*)(smem + SGD_OFF);    // [k*19+{0..16:gdesc,17:eij}]
    float* su    = (float*)(smem + SU_OFF);     // [3k+c]
    float* sfc   = (float*)(smem + SFC_OFF);
    float* sfk   = (float*)(smem + SFK_OFF);
    float* sd    = (float*)(smem + SD_OFF);
    float* scm   = (float*)(smem + SCM_OFF);    // C_m, m=0..11
    float* se    = (float*)(smem + SE_OFF);     // [w*48+row]
    float* sgf4  = (float*)(smem + SGF4_OFF);   // [w*48+l]
    float* sgu4  = (float*)(smem + SGU4_OFF);   // [(w*48+k)*3+c]

    const int t = threadIdx.x;
    const int base3 = blockIdx.x * (K * 3);

    // ---- phase 0: per-pair geometry; C_m table ----
    if (t < K) {
        const float x = rij[base3 + 3 * t];
        const float y = rij[base3 + 3 * t + 1];
        const float z = rij[base3 + 3 * t + 2];
        const float d = sqrtf(x * x + y * y + z * z);
        const float inv = 1.0f / fmaxf(d, 1e-12f);
        su[3 * t] = x * inv; su[3 * t + 1] = y * inv; su[3 * t + 2] = z * inv;
        sd[t] = d;
        sfk[t] = 0.5f + 0.5f * __cosf(POC * d);
        sfc[t] = (d > RMIN_F) ? (0.5f + 0.5f * __cosf(AFC * (d - RMIN_F))) : 1.0f;
#pragma unroll
        for (int c = ND; c < 32; c++) descS[t * 40 + c] = 0;  // K-pad
    }
    if (t >= 64 && t < 64 + NM) {
        const int m = t - 64;
        scm[m] = __expf(CMC * (float)(m * m));
    }
    __syncthreads();

    // ---- phase 1: cosang, fixed-(ch,k) layout (no per-item div/mod) ----
    if (t < 192) {
        const int ch = t / 48, k = t - ch * 48;
        const float ukx = su[3 * k], uky = su[3 * k + 1], ukz = su[3 * k + 2];
        float* scrow = &sc[k * 49 + ch * 12];
        const float* sul = &su[3 * (ch * 12)];
#pragma unroll
        for (int li = 0; li < 12; li++) {
            const int l = ch * 12 + li;
            const float c = ukx * sul[3 * li] + uky * sul[3 * li + 1] + ukz * sul[3 * li + 2];
            scrow[li] = (k == l) ? 0.0f : c;
        }
    }
    __syncthreads();

    // ---- phase 2: waves 0-2 (192 thr): 3-body partials; wave 3: rbf ----
    if (t < 192) {
        const int ch = t / 48, k = t - ch * 48;
        const float* scrow = &sc[k * 49 + ch * 12];
        float part[NM];
#pragma unroll
        for (int m = 0; m < NM; m++) part[m] = 0.0f;
#pragma unroll
        for (int li = 0; li < 12; li++) {
            const int l = ch * 12 + li;
            const float cp1 = scrow[li] + 1.0f;
            const float e0 = __expf(-4.0f * cp1 * cp1) * sfk[l];
            const float e1 = __expf(E1C * cp1);
            float tm = e0;
            part[0] += tm;
#pragma unroll
            for (int m = 1; m < NM; m++) { tm *= e1; part[m] += tm; }
        }
        float* sp = &spart[(ch * 48 + k) * 13];
#pragma unroll
        for (int m = 0; m < NM; m++) sp[m] = part[m];
    } else {
#pragma unroll
        for (int r = 0; r < 4; r++) {
            const int idx = (t - 192) + 64 * r;     // 240 = 48 pairs x 5 rbf
            if (idx < K * NR) {
                const int p = idx / NR, n = idx - NR * p;
                const float d = sd[p];
                const float s = SQ * sfc[p] / d;
                descS[p * 40 + n] = (short)f2bs(s * __sinf((float)(n + 1) * POC * d));
            }
        }
    }
    __syncthreads();

    // ---- phase 3: reduce partials -> desc cols 5..16 (shift layout) ----
    if (t < 192) {
        const int k = t >> 2, q = t & 3;   // 3 m's per thread
#pragma unroll
        for (int i = 0; i < 3; i++) {
            const int m = q * 3 + i;
            const float s = spart[(0 * 48 + k) * 13 + m] + spart[(1 * 48 + k) * 13 + m]
                          + spart[(2 * 48 + k) * 13 + m] + spart[(3 * 48 + k) * 13 + m];
            descS[k * 40 + NR + m] = (short)f2bs(s * scm[m]);
        }
    }
    __syncthreads();

    const int w = t >> 6, lane = t & 63, quad = lane >> 4, lm = lane & 15;
    const int n0 = w * 16 + lm;

    // ---- phase 4 (fwd1): h1 = tanh(desc @ W1 + b1); t1 in registers ----
    float t1[3][4];
    {
        const frag_ab bf = *(const frag_ab*)&g_w1t[n0 * 32 + quad * 8];
        const float bias = b1[n0];
#pragma unroll
        for (int mt = 0; mt < 3; mt++) {
            const frag_ab a = *(const frag_ab*)&descS[(mt * 16 + lm) * 40 + quad * 8];
            frag_cd acc = {bias, bias, bias, bias};
            acc = __builtin_amdgcn_mfma_f32_16x16x32_bf16(a, bf, acc, 0, 0, 0);
#pragma unroll
            for (int r = 0; r < 4; r++) {
                const float tv = fast_tanh(acc[r]);
                t1[mt][r] = tv;
                h1S[(mt * 16 + quad * 4 + r) * 72 + n0] = (short)f2bs(tv);
            }
        }
    }
    __syncthreads();

    // ---- phase 5 (fwd2): t2 = tanh(h1@W2+b2); e partials; gz2 ----
    {
        const frag_ab b0 = *(const frag_ab*)&g_w2t[n0 * 64 + quad * 8];
        const frag_ab b1f = *(const frag_ab*)&g_w2t[n0 * 64 + 32 + quad * 8];
        const float bias = b2[n0];
        const float w3n = W3[n0];
#pragma unroll
        for (int mt = 0; mt < 3; mt++) {
            const frag_ab a0 = *(const frag_ab*)&h1S[(mt * 16 + lm) * 72 + quad * 8];
            const frag_ab a1 = *(const frag_ab*)&h1S[(mt * 16 + lm) * 72 + 32 + quad * 8];
            frag_cd acc = {bias, bias, bias, bias};
            acc = __builtin_amdgcn_mfma_f32_16x16x32_bf16(a0, b0, acc, 0, 0, 0);
            acc = __builtin_amdgcn_mfma_f32_16x16x32_bf16(a1, b1f, acc, 0, 0, 0);
            float ep[4];
#pragma unroll
            for (int r = 0; r < 4; r++) {
                const int row = mt * 16 + quad * 4 + r;
                const float tv = fast_tanh(acc[r]);
                ep[r] = tv * w3n;
                gz2S[row * 72 + n0] = (short)f2bs(sfc[row] * w3n * (1.0f - tv * tv));
            }
#pragma unroll
            for (int off = 1; off < 16; off <<= 1) {
#pragma unroll
                for (int r = 0; r < 4; r++) ep[r] += __shfl_xor(ep[r], off, 64);
            }
            if (lm == 0) {
#pragma unroll
                for (int r = 0; r < 4; r++) se[w * 48 + mt * 16 + quad * 4 + r] = ep[r];
            }
        }
    }
    __syncthreads();

    // ---- phase 6 (bwd1): gz1 = (gz2 @ W2^T)*(1-t1^2) -> overwrite h1S ----
    {
        const frag_ab b0 = *(const frag_ab*)&g_w2r[n0 * 64 + quad * 8];
        const frag_ab b1f = *(const frag_ab*)&g_w2r[n0 * 64 + 32 + quad * 8];
#pragma unroll
        for (int mt = 0; mt < 3; mt++) {
            const frag_ab a0 = *(const frag_ab*)&gz2S[(mt * 16 + lm) * 72 + quad * 8];
            const frag_ab a1 = *(const frag_ab*)&gz2S[(mt * 16 + lm) * 72 + 32 + quad * 8];
            frag_cd acc = {0.0f, 0.0f, 0.0f, 0.0f};
            acc = __builtin_amdgcn_mfma_f32_16x16x32_bf16(a0, b0, acc, 0, 0, 0);
            acc = __builtin_amdgcn_mfma_f32_16x16x32_bf16(a1, b1f, acc, 0, 0, 0);
#pragma unroll
            for (int r = 0; r < 4; r++) {
                const float g = acc[r] * (1.0f - t1[mt][r] * t1[mt][r]);
                h1S[(mt * 16 + quad * 4 + r) * 72 + n0] = (short)f2bs(g);
            }
        }
    }
    __syncthreads();

    // ---- phase 7 (bwd2): gdesc = gz1 @ W1^T -> sgd; eij from se ----
    for (int tid = w; tid < 6; tid += 4) {
        const int mt = tid >> 1, nt = tid & 1, n = nt * 16 + lm;
        const frag_ab b0 = *(const frag_ab*)&g_w1r[n * 64 + quad * 8];
        const frag_ab b1f = *(const frag_ab*)&g_w1r[n * 64 + 32 + quad * 8];
        const frag_ab a0 = *(const frag_ab*)&h1S[(mt * 16 + lm) * 72 + quad * 8];
        const frag_ab a1 = *(const frag_ab*)&h1S[(mt * 16 + lm) * 72 + 32 + quad * 8];
        frag_cd acc = {0.0f, 0.0f, 0.0f, 0.0f};
        acc = __builtin_amdgcn_mfma_f32_16x16x32_bf16(a0, b0, acc, 0, 0, 0);
        acc = __builtin_amdgcn_mfma_f32_16x16x32_bf16(a1, b1f, acc, 0, 0, 0);
        if (n < ND) {
#pragma unroll
            for (int r = 0; r < 4; r++)
                sgd[(mt * 16 + quad * 4 + r) * 19 + n] = acc[r];
        }
    }
    if (t < K)
        sgd[t * 19 + 17] = se[t] + se[48 + t] + se[96 + t] + se[144 + t] + b3[0];
    __syncthreads();

    // ---- phase 8a: sgG = gdesc_3b * C_m; mgG = m * sgG (shift layout) ----
    if (t < 192) {
        const int k = t >> 2, q = t & 3;
#pragma unroll
        for (int i = 0; i < 3; i++) {
            const int m = q * 3 + i;
            const float g = sgd[k * 19 + NR + m] * scm[m];
            sgG[k * 12 + m] = g;
            mgG[k * 12 + m] = (float)m * g;
        }
    }
    __syncthreads();

    // ---- phase 8b: fixed-k dual Horner: T = e0*P(x), U = e0*x*P'(x) ----
    if (t < 192) {
        const int ch = t / 48, k = t - ch * 48;
        float gg[NM], mg[NM];
#pragma unroll
        for (int m = 0; m < NM; m++) { gg[m] = sgG[k * 12 + m]; mg[m] = mgG[k * 12 + m]; }
        float* scrow = &sc[k * 49 + ch * 12];
        float* strow = &sT[k * 48 + ch * 12];
#pragma unroll
        for (int li = 0; li < 12; li++) {
            const int l = ch * 12 + li;
            const float cp1 = scrow[li] + 1.0f;
            const float e0 = __expf(-4.0f * cp1 * cp1);
            const float x = __expf(E1C * cp1);
            float Pv = gg[11], Dv = mg[11];
#pragma unroll
            for (int m = 10; m >= 1; m--) {
                Pv = fmaf(Pv, x, gg[m]);
                Dv = fmaf(Dv, x, mg[m]);
            }
            Pv = fmaf(Pv, x, gg[0]);
            const float T = e0 * Pv;
            const float U = e0 * x * Dv;
            const float Sp = fmaf(cp1, T, -(2.0f / 11.0f) * U);
            strow[li] = T;
            scrow[li] = (k == l) ? 0.0f : (-8.0f) * Sp;
        }
    }
    __syncthreads();

    // ---- phase 8c: partial reductions, all 4 waves ----
    if (lane < K) {
        float s = 0.0f;
#pragma unroll
        for (int kk = 12 * w; kk < 12 * w + 12; kk++) s += sT[kk * 48 + lane];
        sgf4[w * 48 + lane] = s;

        const int k = lane;
        const float fk = sfk[k];
        float gx = 0.0f, gy = 0.0f, gz = 0.0f;
#pragma unroll
        for (int l = 12 * w; l < 12 * w + 12; l++) {
            const float wgt = fmaf(sc[k * 49 + l], sfk[l], sc[l * 49 + k] * fk);
            gx = fmaf(wgt, su[3 * l], gx);
            gy = fmaf(wgt, su[3 * l + 1], gy);
            gz = fmaf(wgt, su[3 * l + 2], gz);
        }
        sgu4[(w * 48 + k) * 3 + 0] = gx;
        sgu4[(w * 48 + k) * 3 + 1] = gy;
        sgu4[(w * 48 + k) * 3 + 2] = gz;
    }
    __syncthreads();

    // ---- phase 8d: combine partials, assemble gradient, write out ----
    if (t < K) {
        const float sgf_t = sgf4[t] + sgf4[48 + t] + sgf4[96 + t] + sgf4[144 + t];
        float gux = 0.0f, guy = 0.0f, guz = 0.0f;
#pragma unroll
        for (int ww = 0; ww < 4; ww++) {
            gux += sgu4[(ww * 48 + t) * 3 + 0];
            guy += sgu4[(ww * 48 + t) * 3 + 1];
            guz += sgu4[(ww * 48 + t) * 3 + 2];
        }
        const float d = sd[t];
        const float ux = su[3 * t], uy = su[3 * t + 1], uz = su[3 * t + 2];
        const float invd = 1.0f / d;
        float gfc = sgd[t * 19 + 17];
        float gdR = 0.0f;
#pragma unroll
        for (int n = 0; n < NR; n++) {
            const float bn = (float)(n + 1) * POC;
            float sn, cn;
            __sincosf(bn * d, &sn, &cn);
            const float g = sgd[t * 19 + n];
            gfc = fmaf(g, SQ * sn * invd, gfc);
            gdR = fmaf(g, SQ * (bn * cn - sn * invd) * invd, gdR);
        }
        const float fc = sfc[t];
        float dfc = 0.0f;
        if (d > RMIN_F) dfc = -0.5f * AFC * __sinf(AFC * (d - RMIN_F));
        const float dfcrik = -0.5f * POC * __sinf(POC * d);

        const float gd = fc * gdR + gfc * dfc + sgf_t * dfcrik;
        const float dot = gux * ux + guy * uy + guz * uz;

        out[base3 + 3 * t + 0] = fmaf(gd, ux, (gux - dot * ux) * invd);
        out[base3 + 3 * t + 1] = fmaf(gd, uy, (guy - dot * uy) * invd);
        out[base3 + 3 * t + 2] = fmaf(gd, uz, (guz - dot * uz) * invd);
    }
}

extern "C" void kernel_launch(void* const* d_in, const int* in_sizes, int n_in,
                              void* d_out, int out_size, void* d_ws, size_t ws_size,
                              hipStream_t stream) {
    (void)in_sizes; (void)n_in; (void)out_size; (void)d_ws; (void)ws_size;
    const float* rij = (const float*)d_in[0];
    // d_in[1] = unique_i (unused: dense K neighbors per atom)
    const float* W1 = (const float*)d_in[2];
    const float* b1 = (const float*)d_in[3];
    const float* W2 = (const float*)d_in[4];
    const float* b2 = (const float*)d_in[5];
    const float* W3 = (const float*)d_in[6];
    const float* b3 = (const float*)d_in[7];
    float* out = (float*)d_out;

    k_prep<<<48, 256, 0, stream>>>(W1, W2);
    k_fused<<<NATOMS, 256, 0, stream>>>(rij, b1, b2, W3, b3, out);
}

// Round 12
// 97.552 us; speedup vs baseline: 28.8039x; 1.0114x over previous
//
#include <hip/hip_runtime.h>
#include <hip/hip_bf16.h>

#define NATOMS 2048
#define K 48
#define P (NATOMS * K)
#define NR 5
#define NM 12
#define ND 17
#define HID 64

#define PI_F 3.14159265358979f
#define CUT 3.0f
#define RMIN_F 3.5f
#define AFC (-6.28318530717959f)   /* pi/(CUT-RMIN) = pi/(-0.5) */
#define POC (PI_F / CUT)           /* pi/3 */
#define SQ 0.816496580927726f      /* sqrt(2/3) */
#define E1C 1.45454545454545f      /* 16/11 */
#define CMC (-0.132231404958678f)  /* -16/121 */

// Packed bf16 weight layouts (built once per launch by k_prep).
// Read as MFMA B-fragments directly from global (L2-broadcast).
__device__ unsigned short g_w1t[64 * 32];  // [n=h][k=j]  (k>=17 zero)
__device__ unsigned short g_w2t[64 * 64];  // [n=h2][k=h1]
__device__ unsigned short g_w2r[64 * 64];  // [n=h1][k=h2]
__device__ unsigned short g_w1r[32 * 64];  // [n=j][k=h]  (n>=17 zero)

using frag_ab = __attribute__((ext_vector_type(8))) short;
using frag_cd = __attribute__((ext_vector_type(4))) float;
using f2 = __attribute__((ext_vector_type(2))) float;  // -> v_pk_*_f32

// 5-op tanh: 1 - 2/(e^2x + 1). exp->inf -> 1; exp->0 -> -1 (no clamp).
__device__ __forceinline__ float fast_tanh(float x) {
    const float t = __expf(2.0f * x);
    return 1.0f - 2.0f / (t + 1.0f);
}

__device__ __forceinline__ unsigned short f2bs(float x) {
    __hip_bfloat16 b = __float2bfloat16(x);
    return __builtin_bit_cast(unsigned short, b);
}

// ---------------- Kernel 0: pack weights into MFMA-ready bf16 layouts -----
__global__ __launch_bounds__(256) void k_prep(const float* __restrict__ W1,
                                              const float* __restrict__ W2) {
    const int i = blockIdx.x * 256 + threadIdx.x;  // grid covers 12288
    if (i < 2048) {                                   // W1T[n][k]
        const int n = i >> 5, k = i & 31;
        g_w1t[i] = (k < ND) ? f2bs(W1[k * HID + n]) : (unsigned short)0;
    } else if (i < 2048 + 4096) {                     // W2T[n][k]
        const int j = i - 2048, n = j >> 6, k = j & 63;
        g_w2t[j] = f2bs(W2[k * HID + n]);
    } else if (i < 2048 + 8192) {                     // W2R[n][k]
        const int j = i - (2048 + 4096);
        g_w2r[j] = f2bs(W2[j]);
    } else if (i < 2048 + 8192 + 2048) {              // W1R[n][k]
        const int j = i - (2048 + 8192), n = j >> 6;
        g_w1r[j] = (n < ND) ? f2bs(W1[j]) : (unsigned short)0;
    }
}

// ---------------- Fused kernel: block = 1 atom (48 pairs), 4 waves --------
#define SC_OFF    0        // 48*49*4 = 9408 (persistent; S in-place in 8b)
#define H1_OFF    9408     // 48*72*2 = 6912
#define GZ2_OFF   16320    // 48*72*2 = 6912
#define DESC_OFF  23232    // 48*40*2 = 3840
#define SGD_OFF   27072    // 48*19*4 = 3648
#define SU_OFF    30720    // 576
#define SFC_OFF   31296    // 192
#define SFK_OFF   31488    // 192
#define SD_OFF    31680    // 192
#define SCM_OFF   31872    // 48 (C_m table)
#define SM_BYTES  31920
#define SPART_OFF 9408     // 4*48*13*4 = 9984
#define SGM_OFF   9408     // 48*12*2*4 = 4608 interleaved (g, m*g); ends 14016
#define SGU4_OFF  14016    // 2304 (ends 16320)
#define ST_OFF    16320    // 9216 (ends 25536)
#define SGF4_OFF  25536    // 768 (desc tail; desc dead after ph4)
#define SE_OFF    23232    // 768 (desc head; dead before sT write in 8b)

__global__ __launch_bounds__(256, 5) void k_fused(const float* __restrict__ rij,
                                                  const float* __restrict__ b1,
                                                  const float* __restrict__ b2,
                                                  const float* __restrict__ W3,
                                                  const float* __restrict__ b3,
                                                  float* __restrict__ out) {
    __shared__ __align__(16) char smem[SM_BYTES];
    float* sc    = (float*)(smem + SC_OFF);     // [k*49+l]
    short* h1S   = (short*)(smem + H1_OFF);     // [row*72+n]
    short* gz2S  = (short*)(smem + GZ2_OFF);    // [row*72+n]
    short* descS = (short*)(smem + DESC_OFF);   // [row*40+j]
    float* spart = (float*)(smem + SPART_OFF);  // [(ch*48+k)*13+m]
    float* sgm   = (float*)(smem + SGM_OFF);    // [k*24 + 2m + {0:g,1:m*g}]
    float* sT    = (float*)(smem + ST_OFF);     // [k*48+l]
    float* sgd   = (float*)(smem + SGD_OFF);    // [k*19+{0..16:gdesc,17:eij}]
    float* su    = (float*)(smem + SU_OFF);     // [3k+c]
    float* sfc   = (float*)(smem + SFC_OFF);
    float* sfk   = (float*)(smem + SFK_OFF);
    float* sd    = (float*)(smem + SD_OFF);
    float* scm   = (float*)(smem + SCM_OFF);    // C_m, m=0..11
    float* se    = (float*)(smem + SE_OFF);     // [w*48+row]
    float* sgf4  = (float*)(smem + SGF4_OFF);   // [w*48+l]
    float* sgu4  = (float*)(smem + SGU4_OFF);   // [(w*48+k)*3+c]

    const int t = threadIdx.x;
    const int base3 = blockIdx.x * (K * 3);

    // ---- phase 0: per-pair geometry; C_m table ----
    if (t < K) {
        const float x = rij[base3 + 3 * t];
        const float y = rij[base3 + 3 * t + 1];
        const float z = rij[base3 + 3 * t + 2];
        const float d = sqrtf(x * x + y * y + z * z);
        const float inv = 1.0f / fmaxf(d, 1e-12f);
        su[3 * t] = x * inv; su[3 * t + 1] = y * inv; su[3 * t + 2] = z * inv;
        sd[t] = d;
        sfk[t] = 0.5f + 0.5f * __cosf(POC * d);
        sfc[t] = (d > RMIN_F) ? (0.5f + 0.5f * __cosf(AFC * (d - RMIN_F))) : 1.0f;
#pragma unroll
        for (int c = ND; c < 32; c++) descS[t * 40 + c] = 0;  // K-pad
    }
    if (t >= 64 && t < 64 + NM) {
        const int m = t - 64;
        scm[m] = __expf(CMC * (float)(m * m));
    }
    __syncthreads();

    // ---- phase 1+2 merged: cosang (reg) -> sc; 3-body partials; rbf ----
    if (t < 192) {
        const int ch = t / 48, k = t - ch * 48;
        const float ukx = su[3 * k], uky = su[3 * k + 1], ukz = su[3 * k + 2];
        float* scrow = &sc[k * 49 + ch * 12];
        const float* sul = &su[3 * (ch * 12)];
        f2 partv[6];
#pragma unroll
        for (int i = 0; i < 6; i++) partv[i] = (f2){0.0f, 0.0f};
#pragma unroll
        for (int li = 0; li < 12; li++) {
            const int l = ch * 12 + li;
            float c = ukx * sul[3 * li] + uky * sul[3 * li + 1] + ukz * sul[3 * li + 2];
            if (k == l) c = 0.0f;
            scrow[li] = c;
            const float cp1 = c + 1.0f;
            const float e0 = __expf(-4.0f * cp1 * cp1) * sfk[l];
            const float e1 = __expf(E1C * cp1);
            const float e2s = e1 * e1;
            const f2 e2v = {e2s, e2s};
            f2 tm = {e0, e0 * e1};        // (m=0, m=1)
            partv[0] += tm;
#pragma unroll
            for (int i = 1; i < 6; i++) { tm *= e2v; partv[i] += tm; }
        }
        float* sp = &spart[(ch * 48 + k) * 13];
#pragma unroll
        for (int i = 0; i < 6; i++) { sp[2 * i] = partv[i].x; sp[2 * i + 1] = partv[i].y; }
    } else {
#pragma unroll
        for (int r = 0; r < 4; r++) {
            const int idx = (t - 192) + 64 * r;     // 240 = 48 pairs x 5 rbf
            if (idx < K * NR) {
                const int p = idx / NR, n = idx - NR * p;
                const float d = sd[p];
                const float s = SQ * sfc[p] / d;
                descS[p * 40 + n] = (short)f2bs(s * __sinf((float)(n + 1) * POC * d));
            }
        }
    }
    __syncthreads();

    // ---- phase 3: reduce partials -> desc cols 5..16 (shift layout) ----
    if (t < 192) {
        const int k = t >> 2, q = t & 3;   // 3 m's per thread
#pragma unroll
        for (int i = 0; i < 3; i++) {
            const int m = q * 3 + i;
            const float s = spart[(0 * 48 + k) * 13 + m] + spart[(1 * 48 + k) * 13 + m]
                          + spart[(2 * 48 + k) * 13 + m] + spart[(3 * 48 + k) * 13 + m];
            descS[k * 40 + NR + m] = (short)f2bs(s * scm[m]);
        }
    }
    __syncthreads();

    const int w = t >> 6, lane = t & 63, quad = lane >> 4, lm = lane & 15;
    const int n0 = w * 16 + lm;

    // ---- phase 4 (fwd1): h1 = tanh(desc @ W1 + b1); t1 in registers ----
    float t1[3][4];
    {
        const frag_ab bf = *(const frag_ab*)&g_w1t[n0 * 32 + quad * 8];
        const float bias = b1[n0];
#pragma unroll
        for (int mt = 0; mt < 3; mt++) {
            const frag_ab a = *(const frag_ab*)&descS[(mt * 16 + lm) * 40 + quad * 8];
            frag_cd acc = {bias, bias, bias, bias};
            acc = __builtin_amdgcn_mfma_f32_16x16x32_bf16(a, bf, acc, 0, 0, 0);
#pragma unroll
            for (int r = 0; r < 4; r++) {
                const float tv = fast_tanh(acc[r]);
                t1[mt][r] = tv;
                h1S[(mt * 16 + quad * 4 + r) * 72 + n0] = (short)f2bs(tv);
            }
        }
    }
    __syncthreads();

    // ---- phase 5 (fwd2): t2 = tanh(h1@W2+b2); e partials; gz2 ----
    {
        const frag_ab b0 = *(const frag_ab*)&g_w2t[n0 * 64 + quad * 8];
        const frag_ab b1f = *(const frag_ab*)&g_w2t[n0 * 64 + 32 + quad * 8];
        const float bias = b2[n0];
        const float w3n = W3[n0];
#pragma unroll
        for (int mt = 0; mt < 3; mt++) {
            const frag_ab a0 = *(const frag_ab*)&h1S[(mt * 16 + lm) * 72 + quad * 8];
            const frag_ab a1 = *(const frag_ab*)&h1S[(mt * 16 + lm) * 72 + 32 + quad * 8];
            frag_cd acc = {bias, bias, bias, bias};
            acc = __builtin_amdgcn_mfma_f32_16x16x32_bf16(a0, b0, acc, 0, 0, 0);
            acc = __builtin_amdgcn_mfma_f32_16x16x32_bf16(a1, b1f, acc, 0, 0, 0);
            float ep[4];
#pragma unroll
            for (int r = 0; r < 4; r++) {
                const int row = mt * 16 + quad * 4 + r;
                const float tv = fast_tanh(acc[r]);
                ep[r] = tv * w3n;
                gz2S[row * 72 + n0] = (short)f2bs(sfc[row] * w3n * (1.0f - tv * tv));
            }
#pragma unroll
            for (int off = 1; off < 16; off <<= 1) {
#pragma unroll
                for (int r = 0; r < 4; r++) ep[r] += __shfl_xor(ep[r], off, 64);
            }
            if (lm == 0) {
#pragma unroll
                for (int r = 0; r < 4; r++) se[w * 48 + mt * 16 + quad * 4 + r] = ep[r];
            }
        }
    }
    __syncthreads();

    // ---- phase 6 (bwd1): gz1 = (gz2 @ W2^T)*(1-t1^2) -> overwrite h1S ----
    {
        const frag_ab b0 = *(const frag_ab*)&g_w2r[n0 * 64 + quad * 8];
        const frag_ab b1f = *(const frag_ab*)&g_w2r[n0 * 64 + 32 + quad * 8];
#pragma unroll
        for (int mt = 0; mt < 3; mt++) {
            const frag_ab a0 = *(const frag_ab*)&gz2S[(mt * 16 + lm) * 72 + quad * 8];
            const frag_ab a1 = *(const frag_ab*)&gz2S[(mt * 16 + lm) * 72 + 32 + quad * 8];
            frag_cd acc = {0.0f, 0.0f, 0.0f, 0.0f};
            acc = __builtin_amdgcn_mfma_f32_16x16x32_bf16(a0, b0, acc, 0, 0, 0);
            acc = __builtin_amdgcn_mfma_f32_16x16x32_bf16(a1, b1f, acc, 0, 0, 0);
#pragma unroll
            for (int r = 0; r < 4; r++) {
                const float g = acc[r] * (1.0f - t1[mt][r] * t1[mt][r]);
                h1S[(mt * 16 + quad * 4 + r) * 72 + n0] = (short)f2bs(g);
            }
        }
    }
    __syncthreads();

    // ---- phase 7 (bwd2): gdesc = gz1 @ W1^T -> sgd; eij from se ----
    for (int tid = w; tid < 6; tid += 4) {
        const int mt = tid >> 1, nt = tid & 1, n = nt * 16 + lm;
        const frag_ab b0 = *(const frag_ab*)&g_w1r[n * 64 + quad * 8];
        const frag_ab b1f = *(const frag_ab*)&g_w1r[n * 64 + 32 + quad * 8];
        const frag_ab a0 = *(const frag_ab*)&h1S[(mt * 16 + lm) * 72 + quad * 8];
        const frag_ab a1 = *(const frag_ab*)&h1S[(mt * 16 + lm) * 72 + 32 + quad * 8];
        frag_cd acc = {0.0f, 0.0f, 0.0f, 0.0f};
        acc = __builtin_amdgcn_mfma_f32_16x16x32_bf16(a0, b0, acc, 0, 0, 0);
        acc = __builtin_amdgcn_mfma_f32_16x16x32_bf16(a1, b1f, acc, 0, 0, 0);
        if (n < ND) {
#pragma unroll
            for (int r = 0; r < 4; r++)
                sgd[(mt * 16 + quad * 4 + r) * 19 + n] = acc[r];
        }
    }
    if (t < K)
        sgd[t * 19 + 17] = se[t] + se[48 + t] + se[96 + t] + se[144 + t] + b3[0];
    __syncthreads();

    // ---- phase 8a: sgm = interleaved (g*C_m, m*g*C_m) ----
    if (t < 192) {
        const int k = t >> 2, q = t & 3;
#pragma unroll
        for (int i = 0; i < 3; i++) {
            const int m = q * 3 + i;
            const float g = sgd[k * 19 + NR + m] * scm[m];
            *(f2*)&sgm[k * 24 + 2 * m] = (f2){g, (float)m * g};
        }
    }
    __syncthreads();

    // ---- phase 8b: fixed-k packed dual Horner: (P, D) in one f2 chain ----
    if (t < 192) {
        const int ch = t / 48, k = t - ch * 48;
        f2 gm[NM];
#pragma unroll
        for (int m = 0; m < NM; m++) gm[m] = *(const f2*)&sgm[k * 24 + 2 * m];
        float* scrow = &sc[k * 49 + ch * 12];
        float* strow = &sT[k * 48 + ch * 12];
#pragma unroll
        for (int li = 0; li < 12; li++) {
            const int l = ch * 12 + li;
            const float cp1 = scrow[li] + 1.0f;
            const float e0 = __expf(-4.0f * cp1 * cp1);
            const float x = __expf(E1C * cp1);
            const f2 xx = {x, x};
            f2 pd = gm[11];
#pragma unroll
            for (int m = 10; m >= 1; m--) pd = __builtin_elementwise_fma(pd, xx, gm[m]);
            const float Pv = fmaf(pd.x, x, gm[0].x);
            const float T = e0 * Pv;
            const float U = e0 * x * pd.y;
            const float Sp = fmaf(cp1, T, -(2.0f / 11.0f) * U);
            strow[li] = T;
            scrow[li] = (k == l) ? 0.0f : (-8.0f) * Sp;
        }
    }
    __syncthreads();

    // ---- phase 8c: partial reductions, all 4 waves ----
    if (lane < K) {
        float s = 0.0f;
#pragma unroll
        for (int kk = 12 * w; kk < 12 * w + 12; kk++) s += sT[kk * 48 + lane];
        sgf4[w * 48 + lane] = s;

        const int k = lane;
        const float fk = sfk[k];
        float gx = 0.0f, gy = 0.0f, gz = 0.0f;
#pragma unroll
        for (int l = 12 * w; l < 12 * w + 12; l++) {
            const float wgt = fmaf(sc[k * 49 + l], sfk[l], sc[l * 49 + k] * fk);
            gx = fmaf(wgt, su[3 * l], gx);
            gy = fmaf(wgt, su[3 * l + 1], gy);
            gz = fmaf(wgt, su[3 * l + 2], gz);
        }
        sgu4[(w * 48 + k) * 3 + 0] = gx;
        sgu4[(w * 48 + k) * 3 + 1] = gy;
        sgu4[(w * 48 + k) * 3 + 2] = gz;
    }
    __syncthreads();

    // ---- phase 8d: combine partials, assemble gradient, write out ----
    if (t < K) {
        const float sgf_t = sgf4[t] + sgf4[48 + t] + sgf4[96 + t] + sgf4[144 + t];
        float gux = 0.0f, guy = 0.0f, guz = 0.0f;
#pragma unroll
        for (int ww = 0; ww < 4; ww++) {
            gux += sgu4[(ww * 48 + t) * 3 + 0];
            guy += sgu4[(ww * 48 + t) * 3 + 1];
            guz += sgu4[(ww * 48 + t) * 3 + 2];
        }
        const float d = sd[t];
        const float ux = su[3 * t], uy = su[3 * t + 1], uz = su[3 * t + 2];
        const float invd = 1.0f / d;
        float gfc = sgd[t * 19 + 17];
        float gdR = 0.0f;
#pragma unroll
        for (int n = 0; n < NR; n++) {
            const float bn = (float)(n + 1) * POC;
            float sn, cn;
            __sincosf(bn * d, &sn, &cn);
            const float g = sgd[t * 19 + n];
            gfc = fmaf(g, SQ * sn * invd, gfc);
            gdR = fmaf(g, SQ * (bn * cn - sn * invd) * invd, gdR);
        }
        const float fc = sfc[t];
        float dfc = 0.0f;
        if (d > RMIN_F) dfc = -0.5f * AFC * __sinf(AFC * (d - RMIN_F));
        const float dfcrik = -0.5f * POC * __sinf(POC * d);

        const float gd = fc * gdR + gfc * dfc + sgf_t * dfcrik;
        const float dot = gux * ux + guy * uy + guz * uz;

        out[base3 + 3 * t + 0] = fmaf(gd, ux, (gux - dot * ux) * invd);
        out[base3 + 3 * t + 1] = fmaf(gd, uy, (guy - dot * uy) * invd);
        out[base3 + 3 * t + 2] = fmaf(gd, uz, (guz - dot * uz) * invd);
    }
}

extern "C" void kernel_launch(void* const* d_in, const int* in_sizes, int n_in,
                              void* d_out, int out_size, void* d_ws, size_t ws_size,
                              hipStream_t stream) {
    (void)in_sizes; (void)n_in; (void)out_size; (void)d_ws; (void)ws_size;
    const float* rij = (const float*)d_in[0];
    // d_in[1] = unique_i (unused: dense K neighbors per atom)
    const float* W1 = (const float*)d_in[2];
    const float* b1 = (const float*)d_in[3];
    const float* W2 = (const float*)d_in[4];
    const float* b2 = (const float*)d_in[5];
    const float* W3 = (const float*)d_in[6];
    const float* b3 = (const float*)d_in[7];
    float* out = (float*)d_out;

    k_prep<<<48, 256, 0, stream>>>(W1, W2);
    k_fused<<<NATOMS, 256, 0, stream>>>(rij, b1, b2, W3, b3, out);
}